// Round 1
// baseline (276.152 us; speedup 1.0000x reference)
//
#include <hip/hip_runtime.h>
#include <math.h>

#define B_ 256
#define V_ 4096
#define K_ 64
#define MINI 1e-6f

// ---- output layout (floats, concatenated in reference return order) ----
#define TEN_OFF 0                         // temp_exp_n [V,K]
#define TEM_OFF (V_*K_)                   // temp_exp_m [B,K]   = 262144
#define QZ_OFF  (TEM_OFF + B_*K_)         // exp_q_z scalar     = 278528
#define NEN_OFF (QZ_OFF + 1)              // new_exp_n [V,K]    = 278529
#define NEM_OFF (NEN_OFF + V_*K_)         // new_exp_m [B,K]    = 540673

// ---- workspace layout (floats) ----
#define WS_DEN   0                        // den[k] = beta_sum+exp_n_sum
#define WS_RHO   64
#define WS_SCALE 65
#define WS_THETA 128                      // theta [B,K]
#define WS_PHI   (128 + B_*K_)            // phi [V,K] (optional cache)
#define WS_NEED_FLOATS (WS_PHI + V_*K_)

// batch_indices may arrive as int32 (JAX canonicalized) or int64.
// int64 little-endian: odd 32-bit words are the (zero) high halves.
__device__ __forceinline__ int detect_is64(const int* bi) {
    int any = 0;
#pragma unroll
    for (int i = 1; i < 64; i += 2) any |= bi[i];
    return any == 0;
}

__device__ __forceinline__ float wave_sum64(float x) {
    x += __shfl_xor(x, 1);
    x += __shfl_xor(x, 2);
    x += __shfl_xor(x, 4);
    x += __shfl_xor(x, 8);
    x += __shfl_xor(x, 16);
    x += __shfl_xor(x, 32);
    return x;
}

// ---------------------------------------------------------------------------
// k_setup (grid 193 x 256):
//   blk [0,64)    den[k] column sums of beta+exp_n
//   blk [64,128)  theta[b,k] = alpha[k]*pi[idx[b],k] + exp_m[idx[b],k]
//   blk [128,192) zero temp_exp_m region (atomic target; d_out is poisoned)
//   blk 192       zero exp_q_z; compute rho, scale
// ---------------------------------------------------------------------------
__global__ __launch_bounds__(256) void k_setup(
    const float* __restrict__ beta, const float* __restrict__ exp_n,
    const float* __restrict__ alpha, const float* __restrict__ pi,
    const float* __restrict__ exp_m, const int* __restrict__ bidx,
    const int* __restrict__ iterp, const int* __restrict__ cmp,
    const int* __restrict__ bcp,
    float* __restrict__ ws, float* __restrict__ out)
{
    __shared__ float red[256];
    __shared__ int is64s;
    const int blk = blockIdx.x, tid = threadIdx.x;
    if (blk < 64) {
        const int k = blk;
        float p = 0.f;
#pragma unroll
        for (int i = 0; i < 16; i++) {
            const int v = tid + i * 256;
            p += beta[v * K_ + k] + exp_n[v * K_ + k];
        }
        red[tid] = p;
        __syncthreads();
        for (int s = 128; s > 0; s >>= 1) {
            if (tid < s) red[tid] += red[tid + s];
            __syncthreads();
        }
        if (tid == 0) ws[WS_DEN + k] = red[0];
    } else if (blk < 128) {
        if (tid == 0) is64s = detect_is64(bidx);
        __syncthreads();
        const int t = (blk - 64) * 256 + tid;   // < 16384
        const int b = t >> 6, k = t & 63;
        const int idx = is64s ? bidx[2 * b] : bidx[b];
        ws[WS_THETA + t] = alpha[k] * pi[idx * K_ + k] + exp_m[idx * K_ + k];
    } else if (blk < 192) {
        out[TEM_OFF + (blk - 128) * 256 + tid] = 0.f;
    } else {
        if (tid == 0) {
            out[QZ_OFF] = 0.f;
            const int it = iterp[0];
            ws[WS_RHO] = powf((float)(it + 5), -0.9f);
            ws[WS_SCALE] = (float)cmp[0] / (float)bcp[0];
        }
    }
}

// ---------------------------------------------------------------------------
// k_pass_n (grid 512 x 512): block owns 8 v's, 8 waves split b (lane = k).
// Produces temp_exp_n, new_exp_n, exp_q_z (atomic), and caches phi to ws.
// ---------------------------------------------------------------------------
__global__ __launch_bounds__(512) void k_pass_n(
    const int* __restrict__ BOW, const float* __restrict__ beta,
    const float* __restrict__ exp_n,
    float* __restrict__ ws, float* __restrict__ out, const int have_phi)
{
    __shared__ int cnt[8 * 256];       // cnt[vi][b]
    __shared__ float phis[8 * 64];
    __shared__ float red[8 * 512];     // per-wave ten partials
    const int tid = threadIdx.x;
    const int v0 = blockIdx.x * 8;

    if (tid < 256) {  // stage cnt: thread=b reads 8 consecutive v (32B)
        const int4* p = (const int4*)(BOW + tid * V_ + v0);
        const int4 a = p[0], b4 = p[1];
        cnt[0 * 256 + tid] = a.x;  cnt[1 * 256 + tid] = a.y;
        cnt[2 * 256 + tid] = a.z;  cnt[3 * 256 + tid] = a.w;
        cnt[4 * 256 + tid] = b4.x; cnt[5 * 256 + tid] = b4.y;
        cnt[6 * 256 + tid] = b4.z; cnt[7 * 256 + tid] = b4.w;
    }
    {   // stage phi rows; also cache to ws for pass_m
        const int vi = tid >> 6, k = tid & 63;
        const int v = v0 + vi;
        const float ph = (beta[v * K_ + k] + exp_n[v * K_ + k]) / ws[WS_DEN + k];
        phis[tid] = ph;
        if (have_phi) ws[WS_PHI + v * K_ + k] = ph;
    }
    __syncthreads();

    const int w = tid >> 6, lane = tid & 63;
    float ph[8];
#pragma unroll
    for (int vi = 0; vi < 8; vi++) ph[vi] = phis[vi * 64 + lane];
    float ten[8] = {0, 0, 0, 0, 0, 0, 0, 0};
    float ent = 0.f;

    for (int i = 0; i < 32; i++) {
        const int b = w + (i << 3);            // wave-strided b
        const float th = ws[WS_THETA + b * K_ + lane];
#pragma unroll
        for (int vi = 0; vi < 8; vi++) {
            const int c = cnt[vi * 256 + b];   // wave-uniform -> scalar branch
            if (c) {
                const float g = th * ph[vi];
                const float s = wave_sum64(g);
                const float gn = g * __builtin_amdgcn_rcpf(s + MINI);
                ten[vi] = fmaf(gn, (float)c, ten[vi]);
                ent = fmaf(gn, __logf(gn + MINI), ent);
            }
        }
    }

#pragma unroll
    for (int vi = 0; vi < 8; vi++) red[w * 512 + vi * 64 + lane] = ten[vi];
    const float e = wave_sum64(ent);
    if (lane == 0) atomicAdd(&out[QZ_OFF], e);
    __syncthreads();

    const float rho = ws[WS_RHO], scale = ws[WS_SCALE];
    {   // 512 threads cover 8*64 slots
        const int vi = tid >> 6, k = tid & 63;
        const int v = v0 + vi;
        float t0 = 0.f;
#pragma unroll
        for (int ww = 0; ww < 8; ww++) t0 += red[ww * 512 + tid];
        out[TEN_OFF + v * K_ + k] = t0;
        out[NEN_OFF + v * K_ + k] =
            (1.f - rho) * exp_n[v * K_ + k] + rho * scale * t0;
    }
}

// ---------------------------------------------------------------------------
// k_pass_m (grid 512 x 512): block owns 4 b's x 512 v's; 8 waves split v.
// Accumulates temp_exp_m via one atomicAdd per (b,k) slot per block.
// ---------------------------------------------------------------------------
__global__ __launch_bounds__(512) void k_pass_m(
    const int* __restrict__ BOW, const float* __restrict__ beta,
    const float* __restrict__ exp_n,
    float* __restrict__ ws, float* __restrict__ out, const int have_phi)
{
    __shared__ int cnt[4 * 512];       // cnt[j][vv]
    __shared__ float red[8 * 256];
    const int tid = threadIdx.x;
    const int bg = blockIdx.x & 63;
    const int vc = blockIdx.x >> 6;
    const int b0 = bg * 4;
    const int vbase = vc * 512;

    {   // stage cnt: 4 rows x 512 ints, coalesced int4
        const int j = tid >> 7, col = tid & 127;
        ((int4*)&cnt[j * 512])[col] =
            ((const int4*)(BOW + (b0 + j) * V_ + vbase))[col];
    }
    __syncthreads();

    const int w = tid >> 6, lane = tid & 63;
    float th[4], acc[4] = {0, 0, 0, 0};
#pragma unroll
    for (int j = 0; j < 4; j++) th[j] = ws[WS_THETA + (b0 + j) * K_ + lane];
    const float rden = 1.0f / ws[WS_DEN + lane];

    for (int i = 0; i < 64; i++) {
        const int vv = w + (i << 3);           // [0,512)
        const int v = vbase + vv;
        const float ph = have_phi
            ? ws[WS_PHI + v * K_ + lane]
            : (beta[v * K_ + lane] + exp_n[v * K_ + lane]) * rden;
#pragma unroll
        for (int j = 0; j < 4; j++) {
            const int c = cnt[j * 512 + vv];   // wave-uniform
            if (c) {
                const float g = th[j] * ph;
                const float s = wave_sum64(g);
                const float gn = g * __builtin_amdgcn_rcpf(s + MINI);
                acc[j] = fmaf(gn, (float)c, acc[j]);
            }
        }
    }

#pragma unroll
    for (int j = 0; j < 4; j++) red[w * 256 + j * 64 + lane] = acc[j];
    __syncthreads();
    if (tid < 256) {
        float sum = 0.f;
#pragma unroll
        for (int ww = 0; ww < 8; ww++) sum += red[ww * 256 + tid];
        atomicAdd(&out[TEM_OFF + (b0 + (tid >> 6)) * K_ + (tid & 63)], sum);
    }
}

// ---------------------------------------------------------------------------
// k_final_m (grid 64 x 256): new_exp_m = (1-rho)*exp_m[idx] + rho*temp_exp_m
// ---------------------------------------------------------------------------
__global__ __launch_bounds__(256) void k_final_m(
    const int* __restrict__ bidx, const float* __restrict__ exp_m,
    const float* __restrict__ ws, float* __restrict__ out)
{
    __shared__ int is64s;
    if (threadIdx.x == 0) is64s = detect_is64(bidx);
    __syncthreads();
    const int t = blockIdx.x * 256 + threadIdx.x;  // < 16384
    const int b = t >> 6, k = t & 63;
    const int idx = is64s ? bidx[2 * b] : bidx[b];
    const float rho = ws[WS_RHO];
    out[NEM_OFF + t] = (1.f - rho) * exp_m[idx * K_ + k] + rho * out[TEM_OFF + t];
}

extern "C" void kernel_launch(void* const* d_in, const int* in_sizes, int n_in,
                              void* d_out, int out_size, void* d_ws, size_t ws_size,
                              hipStream_t stream)
{
    const int*   BOW   = (const int*)d_in[0];
    const int*   bidx  = (const int*)d_in[1];
    const float* alpha = (const float*)d_in[2];
    const float* pi    = (const float*)d_in[3];
    const float* exp_m = (const float*)d_in[4];
    const float* beta  = (const float*)d_in[5];
    const float* exp_n = (const float*)d_in[6];
    const int*   iterp = (const int*)d_in[7];
    const int*   cmp   = (const int*)d_in[8];
    const int*   bcp   = (const int*)d_in[9];
    float* out = (float*)d_out;
    float* ws  = (float*)d_ws;

    const int have_phi = (ws_size >= (size_t)WS_NEED_FLOATS * sizeof(float)) ? 1 : 0;

    hipLaunchKernelGGL(k_setup, dim3(193), dim3(256), 0, stream,
                       beta, exp_n, alpha, pi, exp_m, bidx, iterp, cmp, bcp, ws, out);
    hipLaunchKernelGGL(k_pass_n, dim3(V_ / 8), dim3(512), 0, stream,
                       BOW, beta, exp_n, ws, out, have_phi);
    hipLaunchKernelGGL(k_pass_m, dim3(512), dim3(512), 0, stream,
                       BOW, beta, exp_n, ws, out, have_phi);
    hipLaunchKernelGGL(k_final_m, dim3(64), dim3(256), 0, stream,
                       bidx, exp_m, ws, out);
}

// Round 3
// 140.554 us; speedup vs baseline: 1.9647x; 1.9647x over previous
//
#include <hip/hip_runtime.h>
#include <math.h>

#define B_ 256
#define V_ 4096
#define K_ 64
#define MINI 1e-6f

// ---- output layout (floats, concatenated in reference return order) ----
#define TEN_OFF 0                         // temp_exp_n [V,K]
#define TEM_OFF (V_*K_)                   // temp_exp_m [B,K]   = 262144
#define QZ_OFF  (TEM_OFF + B_*K_)         // exp_q_z scalar     = 278528
#define NEN_OFF (QZ_OFF + 1)              // new_exp_n [V,K]    = 278529
#define NEM_OFF (NEN_OFF + V_*K_)         // new_exp_m [B,K]    = 540673

// ---- OLD (fallback) workspace layout (floats) ----
#define WS_DEN   0
#define WS_RHO   64
#define WS_SCALE 65
#define WS_THETA 128
#define WS_PHI   (128 + B_*K_)
#define WS_NEED_FLOATS (WS_PHI + V_*K_)

// ---- NEW workspace layout (floats) ----
#define NWS_DEN   0
#define NWS_RHO   64
#define NWS_SCALE 65
#define NWS_TH    128                      // theta [B,K]
#define NWS_THL   (NWS_TH  + B_*K_)        // theta*log(theta)
#define NWS_PH    (NWS_THL + B_*K_)        // phi [V,K]
#define NWS_PHL   (NWS_PH  + V_*K_)        // phi*log(phi)
#define NWS_END   (NWS_PHL + V_*K_)        // 557184 floats = 2.23 MB

__device__ __forceinline__ int detect_is64(const int* bi) {
    int any = 0;
#pragma unroll
    for (int i = 1; i < 64; i += 2) any |= bi[i];
    return any == 0;
}

__device__ __forceinline__ float wave_sum64(float x) {
    x += __shfl_xor(x, 1);
    x += __shfl_xor(x, 2);
    x += __shfl_xor(x, 4);
    x += __shfl_xor(x, 8);
    x += __shfl_xor(x, 16);
    x += __shfl_xor(x, 32);
    return x;
}

// ===========================================================================
// NEW PATH: GEMM reformulation.
//   s[b,v]   = dot(theta[b,:], phi[v,:]);  W = c/(s+MINI)
//   ten[v,k] = phi[v,k]   * sum_b W[b,v]*theta[b,k]
//   tem[b,k] = theta[b,k] * sum_v W[b,v]*phi[v,k]
//   ent      = sum_{live} (E - s*log(s+MINI))/(s+MINI),
//              E = dot(th*logth, ph) + dot(th, ph*logph)
// ===========================================================================

// k_setup1 (grid 1218 x 256):
//   blk [0,64)      den[k]
//   blk [64,128)    theta, theta*log(theta) -> ws
//   blk [128,1217)  zero out[0 .. 278528]  (TEN, TEM, QZ atomic targets)
//   blk 1217        rho, scale
__global__ __launch_bounds__(256) void k_setup1(
    const float* __restrict__ beta, const float* __restrict__ exp_n,
    const float* __restrict__ alpha, const float* __restrict__ pi,
    const float* __restrict__ exp_m, const int* __restrict__ bidx,
    const int* __restrict__ iterp, const int* __restrict__ cmp,
    const int* __restrict__ bcp,
    float* __restrict__ ws, float* __restrict__ out)
{
    const int blk = blockIdx.x, tid = threadIdx.x;
    if (blk < 64) {
        __shared__ float red[256];
        const int k = blk;
        float p = 0.f;
#pragma unroll
        for (int i = 0; i < 16; i++) {
            const int v = tid + i * 256;
            p += beta[v * K_ + k] + exp_n[v * K_ + k];
        }
        red[tid] = p;
        __syncthreads();
        for (int s = 128; s > 0; s >>= 1) {
            if (tid < s) red[tid] += red[tid + s];
            __syncthreads();
        }
        if (tid == 0) ws[NWS_DEN + k] = red[0];
    } else if (blk < 128) {
        __shared__ int is64s;
        if (tid == 0) is64s = detect_is64(bidx);
        __syncthreads();
        const int t = (blk - 64) * 256 + tid;   // < 16384
        const int b = t >> 6, k = t & 63;
        const int idx = is64s ? bidx[2 * b] : bidx[b];
        const float th = alpha[k] * pi[idx * K_ + k] + exp_m[idx * K_ + k];
        ws[NWS_TH + t] = th;
        ws[NWS_THL + t] = th * __logf(th);
    } else if (blk < 1217) {
        const int t = (blk - 128) * 256 + tid;
        if (t <= QZ_OFF) out[t] = 0.f;
    } else {
        if (tid == 0) {
            ws[NWS_RHO] = powf((float)(iterp[0] + 5), -0.9f);
            ws[NWS_SCALE] = (float)cmp[0] / (float)bcp[0];
        }
    }
}

// k_setup2 (grid 1024 x 256): phi, phi*log(phi) -> ws (needs den)
__global__ __launch_bounds__(256) void k_setup2(
    const float* __restrict__ beta, const float* __restrict__ exp_n,
    float* __restrict__ ws)
{
    const int t = blockIdx.x * 256 + threadIdx.x;   // < 262144
    const int k = t & 63;
    const float ph = (beta[t] + exp_n[t]) / ws[NWS_DEN + k];
    ws[NWS_PH + t] = ph;
    ws[NWS_PHL + t] = ph * __logf(ph);
}

// k_p1 (grid 256 = 64 v-tiles x 4 b-tiles, 256 thr):
//   S/E GEMM (64x64x64, 3 acc) -> W, entropy -> ten GEMM -> atomics
__global__ __launch_bounds__(256, 1) void k_p1(
    const int* __restrict__ BOW, const float* __restrict__ ws,
    float* __restrict__ out)
{
    __shared__ float th_s[64 * 68], thl_s[64 * 68];
    __shared__ float ph_s[64 * 68], phl_s[64 * 68];
    __shared__ float W_s[64 * 68];
    __shared__ int cnt_s[64 * 65];
    __shared__ float entw[4];
    const int tid = threadIdx.x;
    const int vt = blockIdx.x & 63, bt = blockIdx.x >> 6;
    const int b0 = bt * 64, v0 = vt * 64;

    // 64x64 f32 tile = 1024 float4 slots; 256 threads x 4 iterations.
#pragma unroll
    for (int i = 0; i < 4; i++) {
        const int idx4 = i * 256 + tid;            // 0..1023 (float4 units)
        const int r = idx4 >> 4, k4 = idx4 & 15;   // r<64, k4<16
        *(float4*)&th_s [r * 68 + k4 * 4] = *(const float4*)&ws[NWS_TH  + b0 * 64 + idx4 * 4];
        *(float4*)&thl_s[r * 68 + k4 * 4] = *(const float4*)&ws[NWS_THL + b0 * 64 + idx4 * 4];
        *(float4*)&ph_s [r * 68 + k4 * 4] = *(const float4*)&ws[NWS_PH  + v0 * 64 + idx4 * 4];
        *(float4*)&phl_s[r * 68 + k4 * 4] = *(const float4*)&ws[NWS_PHL + v0 * 64 + idx4 * 4];
    }
#pragma unroll
    for (int i = 0; i < 4; i++) {
        const int j = i * 256 + tid;               // 0..1023 (int4 units)
        const int r = j >> 4, c4 = j & 15;
        const int4 q = *(const int4*)&BOW[(b0 + r) * V_ + v0 + c4 * 4];
        cnt_s[r * 65 + c4 * 4 + 0] = q.x;
        cnt_s[r * 65 + c4 * 4 + 1] = q.y;
        cnt_s[r * 65 + c4 * 4 + 2] = q.z;
        cnt_s[r * 65 + c4 * 4 + 3] = q.w;
    }
    __syncthreads();

    const int tb = tid & 15, tv = tid >> 4;
    float s_acc[4][4] = {}, e_acc[4][4] = {};
    for (int kk = 0; kk < 64; kk += 4) {
        float4 at[4], al[4], bp[4], bl[4];
#pragma unroll
        for (int i = 0; i < 4; i++) {
            at[i] = *(const float4*)&th_s [(tb + 16 * i) * 68 + kk];
            al[i] = *(const float4*)&thl_s[(tb + 16 * i) * 68 + kk];
        }
#pragma unroll
        for (int j = 0; j < 4; j++) {
            bp[j] = *(const float4*)&ph_s [(tv + 16 * j) * 68 + kk];
            bl[j] = *(const float4*)&phl_s[(tv + 16 * j) * 68 + kk];
        }
#pragma unroll
        for (int i = 0; i < 4; i++)
#pragma unroll
            for (int j = 0; j < 4; j++) {
                s_acc[i][j] += at[i].x * bp[j].x + at[i].y * bp[j].y
                             + at[i].z * bp[j].z + at[i].w * bp[j].w;
                e_acc[i][j] += al[i].x * bp[j].x + al[i].y * bp[j].y
                             + al[i].z * bp[j].z + al[i].w * bp[j].w
                             + at[i].x * bl[j].x + at[i].y * bl[j].y
                             + at[i].z * bl[j].z + at[i].w * bl[j].w;
            }
    }

    float ent = 0.f;
#pragma unroll
    for (int i = 0; i < 4; i++)
#pragma unroll
        for (int j = 0; j < 4; j++) {
            const int bi = tb + 16 * i, vj = tv + 16 * j;
            const float s = s_acc[i][j];
            const float sm = s + MINI;
            const float r = __builtin_amdgcn_rcpf(sm);
            const int c = cnt_s[bi * 65 + vj];
            W_s[bi * 68 + vj] = (float)c * r;
            if (c) ent += (e_acc[i][j] - s * __logf(sm)) * r;
        }
    ent = wave_sum64(ent);
    if ((tid & 63) == 0) entw[tid >> 6] = ent;
    __syncthreads();                                // also publishes W_s
    if (tid == 0)
        atomicAdd(&out[QZ_OFF], entw[0] + entw[1] + entw[2] + entw[3]);

    // ten GEMM: acc[v,k] = sum_b W[b,v]*th[b,k];  ten = ph .* acc
    const int tk = tid & 15, tv2 = tid >> 4;
    float ta[4][4] = {};
    for (int b = 0; b < 64; b++) {
        const float4 wv = *(const float4*)&W_s[b * 68 + 4 * tv2];
        const float4 t4 = *(const float4*)&th_s[b * 68 + 4 * tk];
        const float* wp = &wv.x;
        const float* tp = &t4.x;
#pragma unroll
        for (int j = 0; j < 4; j++)
#pragma unroll
            for (int c = 0; c < 4; c++) ta[j][c] += wp[j] * tp[c];
    }
#pragma unroll
    for (int j = 0; j < 4; j++)
#pragma unroll
        for (int c = 0; c < 4; c++) {
            const int v = 4 * tv2 + j, k = 4 * tk + c;
            atomicAdd(&out[TEN_OFF + (v0 + v) * 64 + k],
                      ta[j][c] * ph_s[v * 68 + k]);
        }
}

// k_p2 (grid 128 = 4 b-tiles x 32 v-groups of 128, 256 thr):
//   per v-tile: S GEMM -> W; Z[b,k] += W*ph; end: atomics tem
__global__ __launch_bounds__(256, 1) void k_p2(
    const int* __restrict__ BOW, const float* __restrict__ ws,
    float* __restrict__ out)
{
    __shared__ float th_s[64 * 68], ph_s[64 * 68], W_s[64 * 68];
    __shared__ int cnt_s[64 * 65];
    const int tid = threadIdx.x;
    const int bt = blockIdx.x & 3, vg = blockIdx.x >> 2;   // vg 0..31
    const int b0 = bt * 64;

#pragma unroll
    for (int i = 0; i < 4; i++) {
        const int idx4 = i * 256 + tid;            // 0..1023
        const int r = idx4 >> 4, k4 = idx4 & 15;
        *(float4*)&th_s[r * 68 + k4 * 4] = *(const float4*)&ws[NWS_TH + b0 * 64 + idx4 * 4];
    }

    const int tb = tid & 15, tv = tid >> 4;
    const int tk = tid & 15, tb2 = tid >> 4;
    float Z[4][4] = {};

    for (int vtile = 0; vtile < 2; vtile++) {
        const int v0 = vg * 128 + vtile * 64;
        __syncthreads();   // th staged (1st iter); W_s/ph_s reads done (2nd)
#pragma unroll
        for (int i = 0; i < 4; i++) {
            const int idx4 = i * 256 + tid;        // 0..1023
            const int r = idx4 >> 4, k4 = idx4 & 15;
            *(float4*)&ph_s[r * 68 + k4 * 4] = *(const float4*)&ws[NWS_PH + v0 * 64 + idx4 * 4];
        }
#pragma unroll
        for (int i = 0; i < 4; i++) {
            const int j = i * 256 + tid;
            const int r = j >> 4, c4 = j & 15;
            const int4 q = *(const int4*)&BOW[(b0 + r) * V_ + v0 + c4 * 4];
            cnt_s[r * 65 + c4 * 4 + 0] = q.x;
            cnt_s[r * 65 + c4 * 4 + 1] = q.y;
            cnt_s[r * 65 + c4 * 4 + 2] = q.z;
            cnt_s[r * 65 + c4 * 4 + 3] = q.w;
        }
        __syncthreads();

        float s_acc[4][4] = {};
        for (int kk = 0; kk < 64; kk += 4) {
            float4 at[4], bp[4];
#pragma unroll
            for (int i = 0; i < 4; i++)
                at[i] = *(const float4*)&th_s[(tb + 16 * i) * 68 + kk];
#pragma unroll
            for (int j = 0; j < 4; j++)
                bp[j] = *(const float4*)&ph_s[(tv + 16 * j) * 68 + kk];
#pragma unroll
            for (int i = 0; i < 4; i++)
#pragma unroll
                for (int j = 0; j < 4; j++)
                    s_acc[i][j] += at[i].x * bp[j].x + at[i].y * bp[j].y
                                 + at[i].z * bp[j].z + at[i].w * bp[j].w;
        }
#pragma unroll
        for (int i = 0; i < 4; i++)
#pragma unroll
            for (int j = 0; j < 4; j++) {
                const int bi = tb + 16 * i, vj = tv + 16 * j;
                const float r = __builtin_amdgcn_rcpf(s_acc[i][j] + MINI);
                const int c = cnt_s[bi * 65 + vj];
                W_s[bi * 68 + vj] = (float)c * r;
            }
        __syncthreads();

        for (int v = 0; v < 64; v++) {
            const float4 p4 = *(const float4*)&ph_s[v * 68 + 4 * tk];
            const float* pp = &p4.x;
#pragma unroll
            for (int i = 0; i < 4; i++) {
                const float w = W_s[(4 * tb2 + i) * 68 + v];
#pragma unroll
                for (int c = 0; c < 4; c++) Z[i][c] += w * pp[c];
            }
        }
    }
#pragma unroll
    for (int i = 0; i < 4; i++)
#pragma unroll
        for (int c = 0; c < 4; c++) {
            const int b = 4 * tb2 + i, k = 4 * tk + c;
            atomicAdd(&out[TEM_OFF + (b0 + b) * 64 + k],
                      th_s[b * 68 + k] * Z[i][c]);
        }
}

// k_fin (grid 1088 x 256): new_exp_n (blocks 0..1023), new_exp_m (1024..1087)
__global__ __launch_bounds__(256) void k_fin(
    const int* __restrict__ bidx, const float* __restrict__ exp_n,
    const float* __restrict__ exp_m, const float* __restrict__ ws,
    float* __restrict__ out)
{
    __shared__ int is64s;
    const int t = blockIdx.x * 256 + threadIdx.x;
    const float rho = ws[NWS_RHO];
    if (t < V_ * K_) {
        out[NEN_OFF + t] =
            (1.f - rho) * exp_n[t] + rho * ws[NWS_SCALE] * out[TEN_OFF + t];
    } else {
        if (threadIdx.x == 0) is64s = detect_is64(bidx);
        __syncthreads();
        const int tt = t - V_ * K_;                 // < 16384
        const int b = tt >> 6, k = tt & 63;
        const int idx = is64s ? bidx[2 * b] : bidx[b];
        out[NEM_OFF + tt] =
            (1.f - rho) * exp_m[idx * K_ + k] + rho * out[TEM_OFF + tt];
    }
}

// ===========================================================================
// OLD PATH (round-1 kernels) — fallback when ws is too small for the new one.
// ===========================================================================
__global__ __launch_bounds__(256) void k_setup(
    const float* __restrict__ beta, const float* __restrict__ exp_n,
    const float* __restrict__ alpha, const float* __restrict__ pi,
    const float* __restrict__ exp_m, const int* __restrict__ bidx,
    const int* __restrict__ iterp, const int* __restrict__ cmp,
    const int* __restrict__ bcp,
    float* __restrict__ ws, float* __restrict__ out)
{
    __shared__ float red[256];
    __shared__ int is64s;
    const int blk = blockIdx.x, tid = threadIdx.x;
    if (blk < 64) {
        const int k = blk;
        float p = 0.f;
#pragma unroll
        for (int i = 0; i < 16; i++) {
            const int v = tid + i * 256;
            p += beta[v * K_ + k] + exp_n[v * K_ + k];
        }
        red[tid] = p;
        __syncthreads();
        for (int s = 128; s > 0; s >>= 1) {
            if (tid < s) red[tid] += red[tid + s];
            __syncthreads();
        }
        if (tid == 0) ws[WS_DEN + k] = red[0];
    } else if (blk < 128) {
        if (tid == 0) is64s = detect_is64(bidx);
        __syncthreads();
        const int t = (blk - 64) * 256 + tid;
        const int b = t >> 6, k = t & 63;
        const int idx = is64s ? bidx[2 * b] : bidx[b];
        ws[WS_THETA + t] = alpha[k] * pi[idx * K_ + k] + exp_m[idx * K_ + k];
    } else if (blk < 192) {
        out[TEM_OFF + (blk - 128) * 256 + tid] = 0.f;
    } else {
        if (tid == 0) {
            out[QZ_OFF] = 0.f;
            const int it = iterp[0];
            ws[WS_RHO] = powf((float)(it + 5), -0.9f);
            ws[WS_SCALE] = (float)cmp[0] / (float)bcp[0];
        }
    }
}

__global__ __launch_bounds__(512) void k_pass_n(
    const int* __restrict__ BOW, const float* __restrict__ beta,
    const float* __restrict__ exp_n,
    float* __restrict__ ws, float* __restrict__ out, const int have_phi)
{
    __shared__ int cnt[8 * 256];
    __shared__ float phis[8 * 64];
    __shared__ float red[8 * 512];
    const int tid = threadIdx.x;
    const int v0 = blockIdx.x * 8;

    if (tid < 256) {
        const int4* p = (const int4*)(BOW + tid * V_ + v0);
        const int4 a = p[0], b4 = p[1];
        cnt[0 * 256 + tid] = a.x;  cnt[1 * 256 + tid] = a.y;
        cnt[2 * 256 + tid] = a.z;  cnt[3 * 256 + tid] = a.w;
        cnt[4 * 256 + tid] = b4.x; cnt[5 * 256 + tid] = b4.y;
        cnt[6 * 256 + tid] = b4.z; cnt[7 * 256 + tid] = b4.w;
    }
    {
        const int vi = tid >> 6, k = tid & 63;
        const int v = v0 + vi;
        const float ph = (beta[v * K_ + k] + exp_n[v * K_ + k]) / ws[WS_DEN + k];
        phis[tid] = ph;
        if (have_phi) ws[WS_PHI + v * K_ + k] = ph;
    }
    __syncthreads();

    const int w = tid >> 6, lane = tid & 63;
    float ph[8];
#pragma unroll
    for (int vi = 0; vi < 8; vi++) ph[vi] = phis[vi * 64 + lane];
    float ten[8] = {0, 0, 0, 0, 0, 0, 0, 0};
    float ent = 0.f;

    for (int i = 0; i < 32; i++) {
        const int b = w + (i << 3);
        const float th = ws[WS_THETA + b * K_ + lane];
#pragma unroll
        for (int vi = 0; vi < 8; vi++) {
            const int c = cnt[vi * 256 + b];
            if (c) {
                const float g = th * ph[vi];
                const float s = wave_sum64(g);
                const float gn = g * __builtin_amdgcn_rcpf(s + MINI);
                ten[vi] = fmaf(gn, (float)c, ten[vi]);
                ent = fmaf(gn, __logf(gn + MINI), ent);
            }
        }
    }

#pragma unroll
    for (int vi = 0; vi < 8; vi++) red[w * 512 + vi * 64 + lane] = ten[vi];
    const float e = wave_sum64(ent);
    if (lane == 0) atomicAdd(&out[QZ_OFF], e);
    __syncthreads();

    const float rho = ws[WS_RHO], scale = ws[WS_SCALE];
    {
        const int vi = tid >> 6, k = tid & 63;
        const int v = v0 + vi;
        float t0 = 0.f;
#pragma unroll
        for (int ww = 0; ww < 8; ww++) t0 += red[ww * 512 + tid];
        out[TEN_OFF + v * K_ + k] = t0;
        out[NEN_OFF + v * K_ + k] =
            (1.f - rho) * exp_n[v * K_ + k] + rho * scale * t0;
    }
}

__global__ __launch_bounds__(512) void k_pass_m(
    const int* __restrict__ BOW, const float* __restrict__ beta,
    const float* __restrict__ exp_n,
    float* __restrict__ ws, float* __restrict__ out, const int have_phi)
{
    __shared__ int cnt[4 * 512];
    __shared__ float red[8 * 256];
    const int tid = threadIdx.x;
    const int bg = blockIdx.x & 63;
    const int vc = blockIdx.x >> 6;
    const int b0 = bg * 4;
    const int vbase = vc * 512;

    {
        const int j = tid >> 7, col = tid & 127;
        ((int4*)&cnt[j * 512])[col] =
            ((const int4*)(BOW + (b0 + j) * V_ + vbase))[col];
    }
    __syncthreads();

    const int w = tid >> 6, lane = tid & 63;
    float th[4], acc[4] = {0, 0, 0, 0};
#pragma unroll
    for (int j = 0; j < 4; j++) th[j] = ws[WS_THETA + (b0 + j) * K_ + lane];
    const float rden = 1.0f / ws[WS_DEN + lane];

    for (int i = 0; i < 64; i++) {
        const int vv = w + (i << 3);
        const int v = vbase + vv;
        const float ph = have_phi
            ? ws[WS_PHI + v * K_ + lane]
            : (beta[v * K_ + lane] + exp_n[v * K_ + lane]) * rden;
#pragma unroll
        for (int j = 0; j < 4; j++) {
            const int c = cnt[j * 512 + vv];
            if (c) {
                const float g = th[j] * ph;
                const float s = wave_sum64(g);
                const float gn = g * __builtin_amdgcn_rcpf(s + MINI);
                acc[j] = fmaf(gn, (float)c, acc[j]);
            }
        }
    }

#pragma unroll
    for (int j = 0; j < 4; j++) red[w * 256 + j * 64 + lane] = acc[j];
    __syncthreads();
    if (tid < 256) {
        float sum = 0.f;
#pragma unroll
        for (int ww = 0; ww < 8; ww++) sum += red[ww * 256 + tid];
        atomicAdd(&out[TEM_OFF + (b0 + (tid >> 6)) * K_ + (tid & 63)], sum);
    }
}

__global__ __launch_bounds__(256) void k_final_m(
    const int* __restrict__ bidx, const float* __restrict__ exp_m,
    const float* __restrict__ ws, float* __restrict__ out)
{
    __shared__ int is64s;
    if (threadIdx.x == 0) is64s = detect_is64(bidx);
    __syncthreads();
    const int t = blockIdx.x * 256 + threadIdx.x;
    const int b = t >> 6, k = t & 63;
    const int idx = is64s ? bidx[2 * b] : bidx[b];
    const float rho = ws[WS_RHO];
    out[NEM_OFF + t] = (1.f - rho) * exp_m[idx * K_ + k] + rho * out[TEM_OFF + t];
}

extern "C" void kernel_launch(void* const* d_in, const int* in_sizes, int n_in,
                              void* d_out, int out_size, void* d_ws, size_t ws_size,
                              hipStream_t stream)
{
    const int*   BOW   = (const int*)d_in[0];
    const int*   bidx  = (const int*)d_in[1];
    const float* alpha = (const float*)d_in[2];
    const float* pi    = (const float*)d_in[3];
    const float* exp_m = (const float*)d_in[4];
    const float* beta  = (const float*)d_in[5];
    const float* exp_n = (const float*)d_in[6];
    const int*   iterp = (const int*)d_in[7];
    const int*   cmp   = (const int*)d_in[8];
    const int*   bcp   = (const int*)d_in[9];
    float* out = (float*)d_out;
    float* ws  = (float*)d_ws;

    if (ws_size >= (size_t)NWS_END * sizeof(float)) {
        hipLaunchKernelGGL(k_setup1, dim3(1218), dim3(256), 0, stream,
                           beta, exp_n, alpha, pi, exp_m, bidx, iterp, cmp, bcp, ws, out);
        hipLaunchKernelGGL(k_setup2, dim3(1024), dim3(256), 0, stream,
                           beta, exp_n, ws);
        hipLaunchKernelGGL(k_p1, dim3(256), dim3(256), 0, stream, BOW, ws, out);
        hipLaunchKernelGGL(k_p2, dim3(128), dim3(256), 0, stream, BOW, ws, out);
        hipLaunchKernelGGL(k_fin, dim3(1088), dim3(256), 0, stream,
                           bidx, exp_n, exp_m, ws, out);
    } else {
        const int have_phi = (ws_size >= (size_t)WS_NEED_FLOATS * sizeof(float)) ? 1 : 0;
        hipLaunchKernelGGL(k_setup, dim3(193), dim3(256), 0, stream,
                           beta, exp_n, alpha, pi, exp_m, bidx, iterp, cmp, bcp, ws, out);
        hipLaunchKernelGGL(k_pass_n, dim3(V_ / 8), dim3(512), 0, stream,
                           BOW, beta, exp_n, ws, out, have_phi);
        hipLaunchKernelGGL(k_pass_m, dim3(512), dim3(512), 0, stream,
                           BOW, beta, exp_n, ws, out, have_phi);
        hipLaunchKernelGGL(k_final_m, dim3(64), dim3(256), 0, stream,
                           bidx, exp_m, ws, out);
    }
}

// Round 4
// 133.344 us; speedup vs baseline: 2.0710x; 1.0541x over previous
//
#include <hip/hip_runtime.h>
#include <math.h>

#define B_ 256
#define V_ 4096
#define K_ 64
#define MINI 1e-6f

// ---- output layout (floats, concatenated in reference return order) ----
#define TEN_OFF 0                         // temp_exp_n [V,K]
#define TEM_OFF (V_*K_)                   // temp_exp_m [B,K]   = 262144
#define QZ_OFF  (TEM_OFF + B_*K_)         // exp_q_z scalar     = 278528
#define NEN_OFF (QZ_OFF + 1)              // new_exp_n [V,K]    = 278529 (odd!)
#define NEM_OFF (NEN_OFF + V_*K_)         // new_exp_m [B,K]    = 540673 (odd!)

// ---- workspace layout (floats): den[64], rho, scale ----
#define WS_DEN   0
#define WS_RHO   64
#define WS_SCALE 65

// batch_indices may arrive as int32 (JAX canonicalized) or int64.
__device__ __forceinline__ int detect_is64(const int* bi) {
    int any = 0;
#pragma unroll
    for (int i = 1; i < 64; i += 2) any |= bi[i];
    return any == 0;
}

__device__ __forceinline__ float wave_sum64(float x) {
    x += __shfl_xor(x, 1);
    x += __shfl_xor(x, 2);
    x += __shfl_xor(x, 4);
    x += __shfl_xor(x, 8);
    x += __shfl_xor(x, 16);
    x += __shfl_xor(x, 32);
    return x;
}

// ---------------------------------------------------------------------------
// k_pre (grid 337 x 256):
//   blk [0,64)    den[k] = sum_v beta[v,k]+exp_n[v,k]
//   blk [64,336)  zero out[0..278528) via float4 (TEN+TEM atomic targets)
//   blk 336       zero QZ; rho, scale
// ---------------------------------------------------------------------------
__global__ __launch_bounds__(256) void k_pre(
    const float* __restrict__ beta, const float* __restrict__ exp_n,
    const int* __restrict__ iterp, const int* __restrict__ cmp,
    const int* __restrict__ bcp,
    float* __restrict__ ws, float* __restrict__ out)
{
    const int blk = blockIdx.x, tid = threadIdx.x;
    if (blk < 64) {
        __shared__ float red[256];
        const int k = blk;
        float p = 0.f;
#pragma unroll
        for (int i = 0; i < 16; i++) {
            const int v = tid + i * 256;
            p += beta[v * K_ + k] + exp_n[v * K_ + k];
        }
        red[tid] = p;
        __syncthreads();
        for (int s = 128; s > 0; s >>= 1) {
            if (tid < s) red[tid] += red[tid + s];
            __syncthreads();
        }
        if (tid == 0) ws[WS_DEN + k] = red[0];
    } else if (blk < 336) {
        const int t = (blk - 64) * 256 + tid;      // float4 index < 69632
        const float4 z = {0.f, 0.f, 0.f, 0.f};
        *(float4*)&out[t * 4] = z;
    } else {
        if (tid == 0) {
            out[QZ_OFF] = 0.f;
            ws[WS_RHO] = powf((float)(iterp[0] + 5), -0.9f);
            ws[WS_SCALE] = (float)cmp[0] / (float)bcp[0];
        }
    }
}

// ---------------------------------------------------------------------------
// k_main (grid 256 = 4 bt x 64 vt, 256 thr): everything fused.
//   stage: th/thl (gathered pi,exp_m), ph/phl (beta,exp_n,den), cnt (uchar)
//   S/E GEMM (64x64x64) -> W (overlaid on thl), entropy atomic
//   ten GEMM -> atomics to TEN; tem GEMM -> atomics to TEM
// ---------------------------------------------------------------------------
__global__ __launch_bounds__(256, 1) void k_main(
    const int* __restrict__ BOW, const int* __restrict__ bidx,
    const float* __restrict__ alpha, const float* __restrict__ pi,
    const float* __restrict__ exp_m, const float* __restrict__ beta,
    const float* __restrict__ exp_n,
    const float* __restrict__ ws, float* __restrict__ out)
{
    __shared__ float th_s[64 * 68];
    __shared__ float ph_s[64 * 68];
    __shared__ float phl_s[64 * 68];
    __shared__ float wtl_s[64 * 68];       // thl during S/E GEMM; W after
    __shared__ unsigned char cnt_s[64 * 65];
    __shared__ float entw[4];
    __shared__ int is64s;
    const int tid = threadIdx.x;
    const int vt = blockIdx.x & 63, bt = blockIdx.x >> 6;
    const int b0 = bt * 64, v0 = vt * 64;

    if (tid == 0) is64s = detect_is64(bidx);
    __syncthreads();

    {   // staging: thread -> row r (0..63), 16-col chunk q (0..3)
        const int r = tid >> 2, q = tid & 3;
        const int idx = is64s ? bidx[2 * (b0 + r)] : bidx[b0 + r];
        const int v = v0 + r;
#pragma unroll
        for (int c4 = 0; c4 < 4; c4++) {
            const int k = q * 16 + c4 * 4;
            // theta + theta*log(theta)
            const float4 a4 = *(const float4*)&alpha[k];
            const float4 p4 = *(const float4*)&pi[idx * K_ + k];
            const float4 m4 = *(const float4*)&exp_m[idx * K_ + k];
            float4 t, tl;
            t.x = a4.x * p4.x + m4.x;  tl.x = t.x * __logf(t.x);
            t.y = a4.y * p4.y + m4.y;  tl.y = t.y * __logf(t.y);
            t.z = a4.z * p4.z + m4.z;  tl.z = t.z * __logf(t.z);
            t.w = a4.w * p4.w + m4.w;  tl.w = t.w * __logf(t.w);
            *(float4*)&th_s[r * 68 + k]  = t;
            *(float4*)&wtl_s[r * 68 + k] = tl;
            // phi + phi*log(phi)
            const float4 b4 = *(const float4*)&beta[v * K_ + k];
            const float4 e4 = *(const float4*)&exp_n[v * K_ + k];
            const float4 d4 = *(const float4*)&ws[WS_DEN + k];
            float4 p, pl;
            p.x = (b4.x + e4.x) * __builtin_amdgcn_rcpf(d4.x);  pl.x = p.x * __logf(p.x);
            p.y = (b4.y + e4.y) * __builtin_amdgcn_rcpf(d4.y);  pl.y = p.y * __logf(p.y);
            p.z = (b4.z + e4.z) * __builtin_amdgcn_rcpf(d4.z);  pl.z = p.z * __logf(p.z);
            p.w = (b4.w + e4.w) * __builtin_amdgcn_rcpf(d4.w);  pl.w = p.w * __logf(p.w);
            *(float4*)&ph_s[r * 68 + k]  = p;
            *(float4*)&phl_s[r * 68 + k] = pl;
            // counts (0..3) -> uchar
            const int4 cc = *(const int4*)&BOW[(b0 + r) * V_ + v0 + q * 16 + c4 * 4];
            cnt_s[r * 65 + q * 16 + c4 * 4 + 0] = (unsigned char)cc.x;
            cnt_s[r * 65 + q * 16 + c4 * 4 + 1] = (unsigned char)cc.y;
            cnt_s[r * 65 + q * 16 + c4 * 4 + 2] = (unsigned char)cc.z;
            cnt_s[r * 65 + q * 16 + c4 * 4 + 3] = (unsigned char)cc.w;
        }
    }
    __syncthreads();

    // ---- S/E GEMM: s = th . ph ; e = thl . ph + th . phl ----
    const int tb = tid & 15, tv = tid >> 4;
    float s_acc[4][4] = {}, e_acc[4][4] = {};
    for (int kk = 0; kk < 64; kk += 4) {
        float4 at[4], al[4], bp[4], bl[4];
#pragma unroll
        for (int i = 0; i < 4; i++) {
            at[i] = *(const float4*)&th_s [(tb + 16 * i) * 68 + kk];
            al[i] = *(const float4*)&wtl_s[(tb + 16 * i) * 68 + kk];
        }
#pragma unroll
        for (int j = 0; j < 4; j++) {
            bp[j] = *(const float4*)&ph_s [(tv + 16 * j) * 68 + kk];
            bl[j] = *(const float4*)&phl_s[(tv + 16 * j) * 68 + kk];
        }
#pragma unroll
        for (int i = 0; i < 4; i++)
#pragma unroll
            for (int j = 0; j < 4; j++) {
                s_acc[i][j] += at[i].x * bp[j].x + at[i].y * bp[j].y
                             + at[i].z * bp[j].z + at[i].w * bp[j].w;
                e_acc[i][j] += al[i].x * bp[j].x + al[i].y * bp[j].y
                             + al[i].z * bp[j].z + al[i].w * bp[j].w
                             + at[i].x * bl[j].x + at[i].y * bl[j].y
                             + at[i].z * bl[j].z + at[i].w * bl[j].w;
            }
    }
    __syncthreads();   // all reads of wtl_s (thl) done -> safe to overlay W

    // ---- W + entropy ----
    float ent = 0.f;
#pragma unroll
    for (int i = 0; i < 4; i++)
#pragma unroll
        for (int j = 0; j < 4; j++) {
            const int bi = tb + 16 * i, vj = tv + 16 * j;
            const float s = s_acc[i][j];
            const float sm = s + MINI;
            const float r = __builtin_amdgcn_rcpf(sm);
            const int c = (int)cnt_s[bi * 65 + vj];
            wtl_s[bi * 68 + vj] = (float)c * r;      // W
            if (c) ent += (e_acc[i][j] - s * __logf(sm)) * r;
        }
    ent = wave_sum64(ent);
    if ((tid & 63) == 0) entw[tid >> 6] = ent;
    __syncthreads();                                  // publishes W + entw
    if (tid == 0)
        atomicAdd(&out[QZ_OFF], entw[0] + entw[1] + entw[2] + entw[3]);

    // ---- ten GEMM: ta[v,k] = sum_b W[b,v]*th[b,k]; ten += ph .* ta ----
    {
        const int tk = tid & 15, tv2 = tid >> 4;
        float ta[4][4] = {};
        for (int b = 0; b < 64; b++) {
            const float4 wv = *(const float4*)&wtl_s[b * 68 + 4 * tv2];
            const float4 t4 = *(const float4*)&th_s[b * 68 + 4 * tk];
            const float* wp = &wv.x;
            const float* tp = &t4.x;
#pragma unroll
            for (int j = 0; j < 4; j++)
#pragma unroll
                for (int c = 0; c < 4; c++) ta[j][c] += wp[j] * tp[c];
        }
#pragma unroll
        for (int j = 0; j < 4; j++)
#pragma unroll
            for (int c = 0; c < 4; c++) {
                const int v = 4 * tv2 + j, k = 4 * tk + c;
                atomicAdd(&out[TEN_OFF + (v0 + v) * K_ + k],
                          ta[j][c] * ph_s[v * 68 + k]);
            }
    }

    // ---- tem GEMM: Z[b,k] = sum_v W[b,v]*ph[v,k]; tem += th .* Z ----
    {
        const int tk = tid & 15, tb2 = tid >> 4;
        float Z[4][4] = {};
        for (int v = 0; v < 64; v++) {
            const float4 p4 = *(const float4*)&ph_s[v * 68 + 4 * tk];
            const float* pp = &p4.x;
#pragma unroll
            for (int i = 0; i < 4; i++) {
                const float w = wtl_s[(4 * tb2 + i) * 68 + v];
#pragma unroll
                for (int c = 0; c < 4; c++) Z[i][c] += w * pp[c];
            }
        }
#pragma unroll
        for (int i = 0; i < 4; i++)
#pragma unroll
            for (int c = 0; c < 4; c++) {
                const int b = 4 * tb2 + i, k = 4 * tk + c;
                atomicAdd(&out[TEM_OFF + (b0 + b) * K_ + k],
                          th_s[b * 68 + k] * Z[i][c]);
            }
    }
}

// ---------------------------------------------------------------------------
// k_post (grid 272 x 256): new_exp_n (blk 0..255), new_exp_m (blk 256..271)
// Loads are float4-aligned; stores scalar (NEN_OFF/NEM_OFF are odd).
// ---------------------------------------------------------------------------
__global__ __launch_bounds__(256) void k_post(
    const int* __restrict__ bidx, const float* __restrict__ exp_n,
    const float* __restrict__ exp_m, const float* __restrict__ ws,
    float* __restrict__ out)
{
    const int blk = blockIdx.x, tid = threadIdx.x;
    const float rho = ws[WS_RHO];
    if (blk < 256) {
        const int t = blk * 256 + tid;              // float4 idx < 65536
        const float4 e4 = *(const float4*)&exp_n[t * 4];
        const float4 t4 = *(const float4*)&out[TEN_OFF + t * 4];
        const float rs = rho * ws[WS_SCALE];
        out[NEN_OFF + t * 4 + 0] = (1.f - rho) * e4.x + rs * t4.x;
        out[NEN_OFF + t * 4 + 1] = (1.f - rho) * e4.y + rs * t4.y;
        out[NEN_OFF + t * 4 + 2] = (1.f - rho) * e4.z + rs * t4.z;
        out[NEN_OFF + t * 4 + 3] = (1.f - rho) * e4.w + rs * t4.w;
    } else {
        __shared__ int is64s;
        if (tid == 0) is64s = detect_is64(bidx);
        __syncthreads();
        const int tt = (blk - 256) * 256 + tid;     // float4 idx < 4096
        const int b = tt >> 4, q = tt & 15;
        const int idx = is64s ? bidx[2 * b] : bidx[b];
        const float4 m4 = *(const float4*)&exp_m[idx * K_ + q * 4];
        const float4 t4 = *(const float4*)&out[TEM_OFF + tt * 4];
        out[NEM_OFF + tt * 4 + 0] = (1.f - rho) * m4.x + rho * t4.x;
        out[NEM_OFF + tt * 4 + 1] = (1.f - rho) * m4.y + rho * t4.y;
        out[NEM_OFF + tt * 4 + 2] = (1.f - rho) * m4.z + rho * t4.z;
        out[NEM_OFF + tt * 4 + 3] = (1.f - rho) * m4.w + rho * t4.w;
    }
}

extern "C" void kernel_launch(void* const* d_in, const int* in_sizes, int n_in,
                              void* d_out, int out_size, void* d_ws, size_t ws_size,
                              hipStream_t stream)
{
    const int*   BOW   = (const int*)d_in[0];
    const int*   bidx  = (const int*)d_in[1];
    const float* alpha = (const float*)d_in[2];
    const float* pi    = (const float*)d_in[3];
    const float* exp_m = (const float*)d_in[4];
    const float* beta  = (const float*)d_in[5];
    const float* exp_n = (const float*)d_in[6];
    const int*   iterp = (const int*)d_in[7];
    const int*   cmp   = (const int*)d_in[8];
    const int*   bcp   = (const int*)d_in[9];
    float* out = (float*)d_out;
    float* ws  = (float*)d_ws;

    hipLaunchKernelGGL(k_pre, dim3(337), dim3(256), 0, stream,
                       beta, exp_n, iterp, cmp, bcp, ws, out);
    hipLaunchKernelGGL(k_main, dim3(256), dim3(256), 0, stream,
                       BOW, bidx, alpha, pi, exp_m, beta, exp_n, ws, out);
    hipLaunchKernelGGL(k_post, dim3(272), dim3(256), 0, stream,
                       bidx, exp_n, exp_m, ws, out);
}

// Round 5
// 130.779 us; speedup vs baseline: 2.1116x; 1.0196x over previous
//
#include <hip/hip_runtime.h>
#include <math.h>

#define B_ 256
#define V_ 4096
#define K_ 64
#define MINI 1e-6f

// ---- output layout (floats, concatenated in reference return order) ----
#define TEN_OFF 0                         // temp_exp_n [V,K]
#define TEM_OFF (V_*K_)                   // temp_exp_m [B,K]   = 262144
#define QZ_OFF  (TEM_OFF + B_*K_)         // exp_q_z scalar     = 278528
#define NEN_OFF (QZ_OFF + 1)              // new_exp_n [V,K]    = 278529 (odd!)
#define NEM_OFF (NEN_OFF + V_*K_)         // new_exp_m [B,K]    = 540673 (odd!)

// ---- workspace layout (floats) ----
#define WS_RHO   64
#define WS_SCALE 65
#define WS_PART  128                      // den partials [64 groups][64 k]

__device__ __forceinline__ int detect_is64(const int* bi) {
    int any = 0;
#pragma unroll
    for (int i = 1; i < 64; i += 2) any |= bi[i];
    return any == 0;
}

__device__ __forceinline__ float wave_sum64(float x) {
    x += __shfl_xor(x, 1);
    x += __shfl_xor(x, 2);
    x += __shfl_xor(x, 4);
    x += __shfl_xor(x, 8);
    x += __shfl_xor(x, 16);
    x += __shfl_xor(x, 32);
    return x;
}

// ---------------------------------------------------------------------------
// k_pre (grid 337 x 256):
//   blk [0,64)    coalesced den partials: ws[PART + g*64 + k] = sum over the
//                 64 v-rows of group g of (beta+exp_n)[v,k]
//   blk [64,336)  zero out[0..278528) via float4 (TEN+TEM atomic targets)
//   blk 336       zero QZ; rho, scale
// ---------------------------------------------------------------------------
__global__ __launch_bounds__(256) void k_pre(
    const float* __restrict__ beta, const float* __restrict__ exp_n,
    const int* __restrict__ iterp, const int* __restrict__ cmp,
    const int* __restrict__ bcp,
    float* __restrict__ ws, float* __restrict__ out)
{
    const int blk = blockIdx.x, tid = threadIdx.x;
    if (blk < 64) {
        __shared__ float red[256];
        const int k = tid & 63, sub = tid >> 6;      // 4 row-groups
        float p = 0.f;
#pragma unroll
        for (int i = 0; i < 16; i++) {
            const int v = blk * 64 + sub * 16 + i;   // coalesced in k
            p += beta[v * K_ + k] + exp_n[v * K_ + k];
        }
        red[tid] = p;
        __syncthreads();
        if (tid < 64)
            ws[WS_PART + blk * 64 + tid] =
                red[tid] + red[64 + tid] + red[128 + tid] + red[192 + tid];
    } else if (blk < 336) {
        const int t = (blk - 64) * 256 + tid;        // float4 index < 69632
        const float4 z = {0.f, 0.f, 0.f, 0.f};
        *(float4*)&out[t * 4] = z;
    } else {
        if (tid == 0) {
            out[QZ_OFF] = 0.f;
            ws[WS_RHO] = powf((float)(iterp[0] + 5), -0.9f);
            ws[WS_SCALE] = (float)cmp[0] / (float)bcp[0];
        }
    }
}

// ---------------------------------------------------------------------------
// k_main (grid 256 = 4 bt x 64 vt, 512 thr = 8 waves): everything fused.
//   den reduce -> stage th/thl/ph/phl/cnt -> S/E GEMM -> W + entropy ->
//   ten GEMM (atomics to TEN) -> tem GEMM (atomics to TEM)
// ---------------------------------------------------------------------------
__global__ __launch_bounds__(512, 2) void k_main(
    const int* __restrict__ BOW, const int* __restrict__ bidx,
    const float* __restrict__ alpha, const float* __restrict__ pi,
    const float* __restrict__ exp_m, const float* __restrict__ beta,
    const float* __restrict__ exp_n,
    const float* __restrict__ ws, float* __restrict__ out)
{
    __shared__ float th_s[64 * 68];
    __shared__ float ph_s[64 * 68];
    __shared__ float phl_s[64 * 68];
    __shared__ float wtl_s[64 * 68];       // thl during S/E GEMM; W after
    __shared__ unsigned char cnt_s[64 * 65];
    __shared__ float dred[256];
    __shared__ float rden_s[64];           // 1/den[k]
    __shared__ float entw[8];
    __shared__ int is64s;
    const int tid = threadIdx.x;
    const int vt = blockIdx.x & 63, bt = blockIdx.x >> 6;
    const int b0 = bt * 64, v0 = vt * 64;

    // ---- den[k] from 64 coalesced partials ----
    if (tid == 0) is64s = detect_is64(bidx);
    if (tid < 256) {
        const int k = tid & 63, g0 = tid >> 6;       // g0 in 0..3
        float s = 0.f;
#pragma unroll
        for (int i = 0; i < 16; i++)
            s += ws[WS_PART + (g0 + 4 * i) * 64 + k];
        dred[tid] = s;
    }
    __syncthreads();
    if (tid < 64)
        rden_s[tid] = __builtin_amdgcn_rcpf(
            dred[tid] + dred[64 + tid] + dred[128 + tid] + dred[192 + tid]);
    __syncthreads();

    {   // ---- staging: thread -> row r (0..63), 8-col chunk q (0..7) ----
        const int r = tid >> 3, q = tid & 7;
        const int idx = is64s ? bidx[2 * (b0 + r)] : bidx[b0 + r];
        const int v = v0 + r;
#pragma unroll
        for (int c4 = 0; c4 < 2; c4++) {
            const int k = q * 8 + c4 * 4;
            const float4 a4 = *(const float4*)&alpha[k];
            const float4 p4 = *(const float4*)&pi[idx * K_ + k];
            const float4 m4 = *(const float4*)&exp_m[idx * K_ + k];
            float4 t, tl;
            t.x = a4.x * p4.x + m4.x;  tl.x = t.x * __logf(t.x);
            t.y = a4.y * p4.y + m4.y;  tl.y = t.y * __logf(t.y);
            t.z = a4.z * p4.z + m4.z;  tl.z = t.z * __logf(t.z);
            t.w = a4.w * p4.w + m4.w;  tl.w = t.w * __logf(t.w);
            *(float4*)&th_s[r * 68 + k]  = t;
            *(float4*)&wtl_s[r * 68 + k] = tl;
            const float4 b4 = *(const float4*)&beta[v * K_ + k];
            const float4 e4 = *(const float4*)&exp_n[v * K_ + k];
            const float4 d4 = *(const float4*)&rden_s[k];
            float4 p, pl;
            p.x = (b4.x + e4.x) * d4.x;  pl.x = p.x * __logf(p.x);
            p.y = (b4.y + e4.y) * d4.y;  pl.y = p.y * __logf(p.y);
            p.z = (b4.z + e4.z) * d4.z;  pl.z = p.z * __logf(p.z);
            p.w = (b4.w + e4.w) * d4.w;  pl.w = p.w * __logf(p.w);
            *(float4*)&ph_s[r * 68 + k]  = p;
            *(float4*)&phl_s[r * 68 + k] = pl;
            const int4 cc = *(const int4*)&BOW[(b0 + r) * V_ + v0 + k];
            cnt_s[r * 65 + k + 0] = (unsigned char)cc.x;
            cnt_s[r * 65 + k + 1] = (unsigned char)cc.y;
            cnt_s[r * 65 + k + 2] = (unsigned char)cc.z;
            cnt_s[r * 65 + k + 3] = (unsigned char)cc.w;
        }
    }
    __syncthreads();

    // ---- S/E GEMM: 64x64 outputs, acc 4b x 2v per thread ----
    const int tb = tid & 15, tvw = tid >> 4;         // tvw in 0..31
    float s_acc[4][2] = {}, e_acc[4][2] = {};
    for (int kk = 0; kk < 64; kk += 4) {
        float4 at[4], al[4], bp[2], bl[2];
#pragma unroll
        for (int i = 0; i < 4; i++) {
            at[i] = *(const float4*)&th_s [(tb + 16 * i) * 68 + kk];
            al[i] = *(const float4*)&wtl_s[(tb + 16 * i) * 68 + kk];
        }
#pragma unroll
        for (int j = 0; j < 2; j++) {
            bp[j] = *(const float4*)&ph_s [(tvw + 32 * j) * 68 + kk];
            bl[j] = *(const float4*)&phl_s[(tvw + 32 * j) * 68 + kk];
        }
#pragma unroll
        for (int i = 0; i < 4; i++)
#pragma unroll
            for (int j = 0; j < 2; j++) {
                s_acc[i][j] += at[i].x * bp[j].x + at[i].y * bp[j].y
                             + at[i].z * bp[j].z + at[i].w * bp[j].w;
                e_acc[i][j] += al[i].x * bp[j].x + al[i].y * bp[j].y
                             + al[i].z * bp[j].z + al[i].w * bp[j].w
                             + at[i].x * bl[j].x + at[i].y * bl[j].y
                             + at[i].z * bl[j].z + at[i].w * bl[j].w;
            }
    }
    __syncthreads();   // thl reads done -> overlay W

    // ---- W + entropy ----
    float ent = 0.f;
#pragma unroll
    for (int i = 0; i < 4; i++)
#pragma unroll
        for (int j = 0; j < 2; j++) {
            const int bi = tb + 16 * i, vj = tvw + 32 * j;
            const float s = s_acc[i][j];
            const float sm = s + MINI;
            const float r = __builtin_amdgcn_rcpf(sm);
            const int c = (int)cnt_s[bi * 65 + vj];
            wtl_s[bi * 68 + vj] = (float)c * r;      // W
            if (c) ent += (e_acc[i][j] - s * __logf(sm)) * r;
        }
    ent = wave_sum64(ent);
    if ((tid & 63) == 0) entw[tid >> 6] = ent;
    __syncthreads();                                  // publishes W + entw
    if (tid == 0) {
        float e = 0.f;
#pragma unroll
        for (int w = 0; w < 8; w++) e += entw[w];
        atomicAdd(&out[QZ_OFF], e);
    }

    // ---- ten GEMM: ta[v,k] = sum_b W[b,v]*th[b,k]; ten += ph .* ta ----
    {
        const int tk = tid & 15, tv2 = tid >> 4;     // tv2 in 0..31
        float ta[2][4] = {};
        for (int b = 0; b < 64; b++) {
            const float w0 = wtl_s[b * 68 + tv2];
            const float w1 = wtl_s[b * 68 + tv2 + 32];
            const float4 t4 = *(const float4*)&th_s[b * 68 + 4 * tk];
            const float* tp = &t4.x;
#pragma unroll
            for (int c = 0; c < 4; c++) {
                ta[0][c] += w0 * tp[c];
                ta[1][c] += w1 * tp[c];
            }
        }
#pragma unroll
        for (int j = 0; j < 2; j++)
#pragma unroll
            for (int c = 0; c < 4; c++) {
                const int v = tv2 + 32 * j, k = 4 * tk + c;
                atomicAdd(&out[TEN_OFF + (v0 + v) * K_ + k],
                          ta[j][c] * ph_s[v * 68 + k]);
            }
    }

    // ---- tem GEMM: Z[b,k] = sum_v W[b,v]*ph[v,k]; tem += th .* Z ----
    {
        const int tk = tid & 15, tb2 = tid >> 4;     // tb2 in 0..31
        float Z[2][4] = {};
        for (int v = 0; v < 64; v++) {
            const float4 p4 = *(const float4*)&ph_s[v * 68 + 4 * tk];
            const float* pp = &p4.x;
            const float w0 = wtl_s[tb2 * 68 + v];
            const float w1 = wtl_s[(tb2 + 32) * 68 + v];
#pragma unroll
            for (int c = 0; c < 4; c++) {
                Z[0][c] += w0 * pp[c];
                Z[1][c] += w1 * pp[c];
            }
        }
#pragma unroll
        for (int i = 0; i < 2; i++)
#pragma unroll
            for (int c = 0; c < 4; c++) {
                const int b = tb2 + 32 * i, k = 4 * tk + c;
                atomicAdd(&out[TEM_OFF + (b0 + b) * K_ + k],
                          th_s[b * 68 + k] * Z[i][c]);
            }
    }
}

// ---------------------------------------------------------------------------
// k_post (grid 272 x 256): new_exp_n (blk 0..255), new_exp_m (blk 256..271)
// Loads float4; stores scalar (NEN_OFF/NEM_OFF are odd).
// ---------------------------------------------------------------------------
__global__ __launch_bounds__(256) void k_post(
    const int* __restrict__ bidx, const float* __restrict__ exp_n,
    const float* __restrict__ exp_m, const float* __restrict__ ws,
    float* __restrict__ out)
{
    const int blk = blockIdx.x, tid = threadIdx.x;
    const float rho = ws[WS_RHO];
    if (blk < 256) {
        const int t = blk * 256 + tid;              // float4 idx < 65536
        const float4 e4 = *(const float4*)&exp_n[t * 4];
        const float4 t4 = *(const float4*)&out[TEN_OFF + t * 4];
        const float rs = rho * ws[WS_SCALE];
        out[NEN_OFF + t * 4 + 0] = (1.f - rho) * e4.x + rs * t4.x;
        out[NEN_OFF + t * 4 + 1] = (1.f - rho) * e4.y + rs * t4.y;
        out[NEN_OFF + t * 4 + 2] = (1.f - rho) * e4.z + rs * t4.z;
        out[NEN_OFF + t * 4 + 3] = (1.f - rho) * e4.w + rs * t4.w;
    } else {
        __shared__ int is64s;
        if (tid == 0) is64s = detect_is64(bidx);
        __syncthreads();
        const int tt = (blk - 256) * 256 + tid;     // float4 idx < 4096
        const int b = tt >> 4, q = tt & 15;
        const int idx = is64s ? bidx[2 * b] : bidx[b];
        const float4 m4 = *(const float4*)&exp_m[idx * K_ + q * 4];
        const float4 t4 = *(const float4*)&out[TEM_OFF + tt * 4];
        out[NEM_OFF + tt * 4 + 0] = (1.f - rho) * m4.x + rho * t4.x;
        out[NEM_OFF + tt * 4 + 1] = (1.f - rho) * m4.y + rho * t4.y;
        out[NEM_OFF + tt * 4 + 2] = (1.f - rho) * m4.z + rho * t4.z;
        out[NEM_OFF + tt * 4 + 3] = (1.f - rho) * m4.w + rho * t4.w;
    }
}

extern "C" void kernel_launch(void* const* d_in, const int* in_sizes, int n_in,
                              void* d_out, int out_size, void* d_ws, size_t ws_size,
                              hipStream_t stream)
{
    const int*   BOW   = (const int*)d_in[0];
    const int*   bidx  = (const int*)d_in[1];
    const float* alpha = (const float*)d_in[2];
    const float* pi    = (const float*)d_in[3];
    const float* exp_m = (const float*)d_in[4];
    const float* beta  = (const float*)d_in[5];
    const float* exp_n = (const float*)d_in[6];
    const int*   iterp = (const int*)d_in[7];
    const int*   cmp   = (const int*)d_in[8];
    const int*   bcp   = (const int*)d_in[9];
    float* out = (float*)d_out;
    float* ws  = (float*)d_ws;

    hipLaunchKernelGGL(k_pre, dim3(337), dim3(256), 0, stream,
                       beta, exp_n, iterp, cmp, bcp, ws, out);
    hipLaunchKernelGGL(k_main, dim3(256), dim3(512), 0, stream,
                       BOW, bidx, alpha, pi, exp_m, beta, exp_n, ws, out);
    hipLaunchKernelGGL(k_post, dim3(272), dim3(256), 0, stream,
                       bidx, exp_n, exp_m, ws, out);
}

// Round 6
// 103.529 us; speedup vs baseline: 2.6674x; 1.2632x over previous
//
#include <hip/hip_runtime.h>
#include <math.h>

#define B_ 256
#define V_ 4096
#define K_ 64
#define MINI 1e-6f

// ---- output layout (floats, concatenated in reference return order) ----
#define TEN_OFF 0                         // temp_exp_n [V,K]
#define TEM_OFF (V_*K_)                   // temp_exp_m [B,K]   = 262144
#define QZ_OFF  (TEM_OFF + B_*K_)         // exp_q_z scalar     = 278528
#define NEN_OFF (QZ_OFF + 1)              // new_exp_n [V,K]    = 278529 (odd!)
#define NEM_OFF (NEN_OFF + V_*K_)         // new_exp_m [B,K]    = 540673 (odd!)

// ---- workspace layout (floats); ws is 256 MB (verified via R3 fill counter) ----
#define WS_RHO    64
#define WS_SCALE  65
#define WS_PART   128                     // den partials [64 groups][64 k]
#define WS_ENT    4352                    // per-block entropy partials [256]
#define WS_TENP   8192                    // ten partials [4 bt][V,K]  = 4*262144
#define WS_TEMP   (WS_TENP + 4*V_*K_)     // tem tiles [256 blk][64 b][64 k]

__device__ __forceinline__ int detect_is64(const int* bi) {
    int any = 0;
#pragma unroll
    for (int i = 1; i < 64; i += 2) any |= bi[i];
    return any == 0;
}

__device__ __forceinline__ float wave_sum64(float x) {
    x += __shfl_xor(x, 1);
    x += __shfl_xor(x, 2);
    x += __shfl_xor(x, 4);
    x += __shfl_xor(x, 8);
    x += __shfl_xor(x, 16);
    x += __shfl_xor(x, 32);
    return x;
}

// ---------------------------------------------------------------------------
// k_pre (grid 65 x 256):
//   blk [0,64)  coalesced den partials: ws[PART + g*64 + k]
//   blk 64      rho, scale
// ---------------------------------------------------------------------------
__global__ __launch_bounds__(256) void k_pre(
    const float* __restrict__ beta, const float* __restrict__ exp_n,
    const int* __restrict__ iterp, const int* __restrict__ cmp,
    const int* __restrict__ bcp, float* __restrict__ ws)
{
    const int blk = blockIdx.x, tid = threadIdx.x;
    if (blk < 64) {
        __shared__ float red[256];
        const int k = tid & 63, sub = tid >> 6;
        float p = 0.f;
#pragma unroll
        for (int i = 0; i < 16; i++) {
            const int v = blk * 64 + sub * 16 + i;
            p += beta[v * K_ + k] + exp_n[v * K_ + k];
        }
        red[tid] = p;
        __syncthreads();
        if (tid < 64)
            ws[WS_PART + blk * 64 + tid] =
                red[tid] + red[64 + tid] + red[128 + tid] + red[192 + tid];
    } else {
        if (tid == 0) {
            ws[WS_RHO] = powf((float)(iterp[0] + 5), -0.9f);
            ws[WS_SCALE] = (float)cmp[0] / (float)bcp[0];
        }
    }
}

// ---------------------------------------------------------------------------
// k_main (grid 256 = 4 bt x 64 vt, 256 thr): fused, NO atomics.
//   den reduce -> stage th/thl/ph/phl/cnt -> S/E GEMM -> W + ent ->
//   ten GEMM -> private partial store; tem GEMM -> private tile store
// ---------------------------------------------------------------------------
__global__ __launch_bounds__(256, 1) void k_main(
    const int* __restrict__ BOW, const int* __restrict__ bidx,
    const float* __restrict__ alpha, const float* __restrict__ pi,
    const float* __restrict__ exp_m, const float* __restrict__ beta,
    const float* __restrict__ exp_n,
    float* __restrict__ ws)
{
    __shared__ float th_s[64 * 68];
    __shared__ float ph_s[64 * 68];
    __shared__ float phl_s[64 * 68];
    __shared__ float wtl_s[64 * 68];       // thl during S/E GEMM; W after
    __shared__ unsigned char cnt_s[64 * 65];
    __shared__ float dred[256];
    __shared__ float rden_s[64];
    __shared__ float entw[4];
    __shared__ int is64s;
    const int tid = threadIdx.x;
    const int vt = blockIdx.x & 63, bt = blockIdx.x >> 6;
    const int b0 = bt * 64, v0 = vt * 64;

    // ---- den[k] from coalesced partials ----
    if (tid == 0) is64s = detect_is64(bidx);
    {
        const int k = tid & 63, g0 = tid >> 6;
        float s = 0.f;
#pragma unroll
        for (int i = 0; i < 16; i++)
            s += ws[WS_PART + (g0 + 4 * i) * 64 + k];
        dred[tid] = s;
    }
    __syncthreads();
    if (tid < 64)
        rden_s[tid] = __builtin_amdgcn_rcpf(
            dred[tid] + dred[64 + tid] + dred[128 + tid] + dred[192 + tid]);
    __syncthreads();

    {   // ---- staging: row r (0..63), 16-col chunk q (0..3) ----
        const int r = tid >> 2, q = tid & 3;
        const int idx = is64s ? bidx[2 * (b0 + r)] : bidx[b0 + r];
        const int v = v0 + r;
#pragma unroll
        for (int c4 = 0; c4 < 4; c4++) {
            const int k = q * 16 + c4 * 4;
            const float4 a4 = *(const float4*)&alpha[k];
            const float4 p4 = *(const float4*)&pi[idx * K_ + k];
            const float4 m4 = *(const float4*)&exp_m[idx * K_ + k];
            float4 t, tl;
            t.x = a4.x * p4.x + m4.x;  tl.x = t.x * __logf(t.x);
            t.y = a4.y * p4.y + m4.y;  tl.y = t.y * __logf(t.y);
            t.z = a4.z * p4.z + m4.z;  tl.z = t.z * __logf(t.z);
            t.w = a4.w * p4.w + m4.w;  tl.w = t.w * __logf(t.w);
            *(float4*)&th_s[r * 68 + k]  = t;
            *(float4*)&wtl_s[r * 68 + k] = tl;
            const float4 b4 = *(const float4*)&beta[v * K_ + k];
            const float4 e4 = *(const float4*)&exp_n[v * K_ + k];
            const float4 d4 = *(const float4*)&rden_s[k];
            float4 p, pl;
            p.x = (b4.x + e4.x) * d4.x;  pl.x = p.x * __logf(p.x);
            p.y = (b4.y + e4.y) * d4.y;  pl.y = p.y * __logf(p.y);
            p.z = (b4.z + e4.z) * d4.z;  pl.z = p.z * __logf(p.z);
            p.w = (b4.w + e4.w) * d4.w;  pl.w = p.w * __logf(p.w);
            *(float4*)&ph_s[r * 68 + k]  = p;
            *(float4*)&phl_s[r * 68 + k] = pl;
            const int4 cc = *(const int4*)&BOW[(b0 + r) * V_ + v0 + k];
            cnt_s[r * 65 + k + 0] = (unsigned char)cc.x;
            cnt_s[r * 65 + k + 1] = (unsigned char)cc.y;
            cnt_s[r * 65 + k + 2] = (unsigned char)cc.z;
            cnt_s[r * 65 + k + 3] = (unsigned char)cc.w;
        }
    }
    __syncthreads();

    // ---- S/E GEMM ----
    const int tb = tid & 15, tv = tid >> 4;
    float s_acc[4][4] = {}, e_acc[4][4] = {};
    for (int kk = 0; kk < 64; kk += 4) {
        float4 at[4], al[4], bp[4], bl[4];
#pragma unroll
        for (int i = 0; i < 4; i++) {
            at[i] = *(const float4*)&th_s [(tb + 16 * i) * 68 + kk];
            al[i] = *(const float4*)&wtl_s[(tb + 16 * i) * 68 + kk];
        }
#pragma unroll
        for (int j = 0; j < 4; j++) {
            bp[j] = *(const float4*)&ph_s [(tv + 16 * j) * 68 + kk];
            bl[j] = *(const float4*)&phl_s[(tv + 16 * j) * 68 + kk];
        }
#pragma unroll
        for (int i = 0; i < 4; i++)
#pragma unroll
            for (int j = 0; j < 4; j++) {
                s_acc[i][j] += at[i].x * bp[j].x + at[i].y * bp[j].y
                             + at[i].z * bp[j].z + at[i].w * bp[j].w;
                e_acc[i][j] += al[i].x * bp[j].x + al[i].y * bp[j].y
                             + al[i].z * bp[j].z + al[i].w * bp[j].w
                             + at[i].x * bl[j].x + at[i].y * bl[j].y
                             + at[i].z * bl[j].z + at[i].w * bl[j].w;
            }
    }
    __syncthreads();   // thl reads done -> overlay W

    // ---- W + entropy ----
    float ent = 0.f;
#pragma unroll
    for (int i = 0; i < 4; i++)
#pragma unroll
        for (int j = 0; j < 4; j++) {
            const int bi = tb + 16 * i, vj = tv + 16 * j;
            const float s = s_acc[i][j];
            const float sm = s + MINI;
            const float r = __builtin_amdgcn_rcpf(sm);
            const int c = (int)cnt_s[bi * 65 + vj];
            wtl_s[bi * 68 + vj] = (float)c * r;      // W
            if (c) ent += (e_acc[i][j] - s * __logf(sm)) * r;
        }
    ent = wave_sum64(ent);
    if ((tid & 63) == 0) entw[tid >> 6] = ent;
    __syncthreads();                                  // publishes W + entw
    if (tid == 0)
        ws[WS_ENT + blockIdx.x] = entw[0] + entw[1] + entw[2] + entw[3];

    // ---- ten GEMM -> private partial (float4 stores, no atomics) ----
    {
        const int tk = tid & 15, tv2 = tid >> 4;
        float ta[4][4] = {};
        for (int b = 0; b < 64; b++) {
            const float4 wv = *(const float4*)&wtl_s[b * 68 + 4 * tv2];
            const float4 t4 = *(const float4*)&th_s[b * 68 + 4 * tk];
            const float* wp = &wv.x;
            const float* tp = &t4.x;
#pragma unroll
            for (int j = 0; j < 4; j++)
#pragma unroll
                for (int c = 0; c < 4; c++) ta[j][c] += wp[j] * tp[c];
        }
#pragma unroll
        for (int j = 0; j < 4; j++) {
            const int v = 4 * tv2 + j;
            float4 o;
            o.x = ta[j][0] * ph_s[v * 68 + 4 * tk + 0];
            o.y = ta[j][1] * ph_s[v * 68 + 4 * tk + 1];
            o.z = ta[j][2] * ph_s[v * 68 + 4 * tk + 2];
            o.w = ta[j][3] * ph_s[v * 68 + 4 * tk + 3];
            *(float4*)&ws[WS_TENP + bt * (V_ * K_) + (v0 + v) * K_ + 4 * tk] = o;
        }
    }

    // ---- tem GEMM -> private tile (float4 stores, no atomics) ----
    {
        const int tk = tid & 15, tb2 = tid >> 4;
        float Z[4][4] = {};
        for (int v = 0; v < 64; v++) {
            const float4 p4 = *(const float4*)&ph_s[v * 68 + 4 * tk];
            const float* pp = &p4.x;
#pragma unroll
            for (int i = 0; i < 4; i++) {
                const float w = wtl_s[(4 * tb2 + i) * 68 + v];
#pragma unroll
                for (int c = 0; c < 4; c++) Z[i][c] += w * pp[c];
            }
        }
#pragma unroll
        for (int i = 0; i < 4; i++) {
            const int b = 4 * tb2 + i;
            float4 o;
            o.x = th_s[b * 68 + 4 * tk + 0] * Z[i][0];
            o.y = th_s[b * 68 + 4 * tk + 1] * Z[i][1];
            o.z = th_s[b * 68 + 4 * tk + 2] * Z[i][2];
            o.w = th_s[b * 68 + 4 * tk + 3] * Z[i][3];
            *(float4*)&ws[WS_TEMP + blockIdx.x * 4096 + b * K_ + 4 * tk] = o;
        }
    }
}

// ---------------------------------------------------------------------------
// k_post (grid 321 x 256): all reductions + epilogues, no atomics.
//   blk [0,256)   TEN = sum of 4 ten partials; NEN epilogue
//   blk [256,320) TEM = sum of 64 tem tiles; NEM epilogue
//   blk 320       QZ = sum of 256 entropy partials
// ---------------------------------------------------------------------------
__global__ __launch_bounds__(256) void k_post(
    const int* __restrict__ bidx, const float* __restrict__ exp_n,
    const float* __restrict__ exp_m, const float* __restrict__ ws,
    float* __restrict__ out)
{
    const int blk = blockIdx.x, tid = threadIdx.x;
    if (blk < 256) {
        const float rho = ws[WS_RHO];
        const int t = blk * 256 + tid;              // float4 idx < 65536
        const float4 p0 = *(const float4*)&ws[WS_TENP + 0 * (V_ * K_) + t * 4];
        const float4 p1 = *(const float4*)&ws[WS_TENP + 1 * (V_ * K_) + t * 4];
        const float4 p2 = *(const float4*)&ws[WS_TENP + 2 * (V_ * K_) + t * 4];
        const float4 p3 = *(const float4*)&ws[WS_TENP + 3 * (V_ * K_) + t * 4];
        float4 s;
        s.x = (p0.x + p1.x) + (p2.x + p3.x);
        s.y = (p0.y + p1.y) + (p2.y + p3.y);
        s.z = (p0.z + p1.z) + (p2.z + p3.z);
        s.w = (p0.w + p1.w) + (p2.w + p3.w);
        *(float4*)&out[TEN_OFF + t * 4] = s;
        const float4 e4 = *(const float4*)&exp_n[t * 4];
        const float rs = rho * ws[WS_SCALE];
        out[NEN_OFF + t * 4 + 0] = (1.f - rho) * e4.x + rs * s.x;
        out[NEN_OFF + t * 4 + 1] = (1.f - rho) * e4.y + rs * s.y;
        out[NEN_OFF + t * 4 + 2] = (1.f - rho) * e4.z + rs * s.z;
        out[NEN_OFF + t * 4 + 3] = (1.f - rho) * e4.w + rs * s.w;
    } else if (blk < 320) {
        __shared__ int is64s;
        if (tid == 0) is64s = detect_is64(bidx);
        __syncthreads();
        const float rho = ws[WS_RHO];
        const int b = (blk - 256) * 4 + (tid >> 6);  // < 256
        const int k = tid & 63;
        const int bt = b >> 6, r = b & 63;
        float s = 0.f;
#pragma unroll 8
        for (int vt = 0; vt < 64; vt++)
            s += ws[WS_TEMP + (vt * 4 + bt) * 4096 + r * K_ + k];
        out[TEM_OFF + b * K_ + k] = s;
        const int idx = is64s ? bidx[2 * b] : bidx[b];
        out[NEM_OFF + b * K_ + k] =
            (1.f - rho) * exp_m[idx * K_ + k] + rho * s;
    } else {
        __shared__ float red[256];
        red[tid] = ws[WS_ENT + tid];
        __syncthreads();
        for (int s = 128; s > 0; s >>= 1) {
            if (tid < s) red[tid] += red[tid + s];
            __syncthreads();
        }
        if (tid == 0) out[QZ_OFF] = red[0];
    }
}

extern "C" void kernel_launch(void* const* d_in, const int* in_sizes, int n_in,
                              void* d_out, int out_size, void* d_ws, size_t ws_size,
                              hipStream_t stream)
{
    const int*   BOW   = (const int*)d_in[0];
    const int*   bidx  = (const int*)d_in[1];
    const float* alpha = (const float*)d_in[2];
    const float* pi    = (const float*)d_in[3];
    const float* exp_m = (const float*)d_in[4];
    const float* beta  = (const float*)d_in[5];
    const float* exp_n = (const float*)d_in[6];
    const int*   iterp = (const int*)d_in[7];
    const int*   cmp   = (const int*)d_in[8];
    const int*   bcp   = (const int*)d_in[9];
    float* out = (float*)d_out;
    float* ws  = (float*)d_ws;

    hipLaunchKernelGGL(k_pre, dim3(65), dim3(256), 0, stream,
                       beta, exp_n, iterp, cmp, bcp, ws);
    hipLaunchKernelGGL(k_main, dim3(256), dim3(256), 0, stream,
                       BOW, bidx, alpha, pi, exp_m, beta, exp_n, ws);
    hipLaunchKernelGGL(k_post, dim3(321), dim3(256), 0, stream,
                       bidx, exp_n, exp_m, ws, out);
}

// Round 7
// 93.777 us; speedup vs baseline: 2.9448x; 1.1040x over previous
//
#include <hip/hip_runtime.h>
#include <math.h>

#define B_ 256
#define V_ 4096
#define K_ 64
#define MINI 1e-6f

// ---- output layout (floats, concatenated in reference return order) ----
#define TEN_OFF 0                         // temp_exp_n [V,K]
#define TEM_OFF (V_*K_)                   // temp_exp_m [B,K]   = 262144
#define QZ_OFF  (TEM_OFF + B_*K_)         // exp_q_z scalar     = 278528
#define NEN_OFF (QZ_OFF + 1)              // new_exp_n [V,K]    = 278529 (odd!)
#define NEM_OFF (NEN_OFF + V_*K_)         // new_exp_m [B,K]    = 540673 (odd!)

// ---- workspace layout (floats); ws is 256 MB ----
#define WS_RHO    64
#define WS_SCALE  65
#define WS_PART   128                     // den partials [64 groups][64 k]
#define WS_ENT    4352                    // per-block entropy partials [256]
#define WS_TENP   8192                    // ten partials [4 bt][V,K]
#define WS_TEMP   (WS_TENP + 4*V_*K_)     // tem tiles [256 blk][64 b][64 k]

#define LDB 72                            // bf16 LDS row stride (shorts)

typedef __attribute__((ext_vector_type(8))) short bf16x8;
typedef __attribute__((ext_vector_type(4))) float f32x4;

__device__ __forceinline__ short bf(float x) {
    return (short)(__float_as_uint(x) >> 16);   // truncate f32 -> bf16
}

__device__ __forceinline__ int detect_is64(const int* bi) {
    int any = 0;
#pragma unroll
    for (int i = 1; i < 64; i += 2) any |= bi[i];
    return any == 0;
}

__device__ __forceinline__ float wave_sum64(float x) {
    x += __shfl_xor(x, 1);
    x += __shfl_xor(x, 2);
    x += __shfl_xor(x, 4);
    x += __shfl_xor(x, 8);
    x += __shfl_xor(x, 16);
    x += __shfl_xor(x, 32);
    return x;
}

__device__ __forceinline__ bf16x8 ldfrag(const short* arr, int row, int kofs) {
    return *(const bf16x8*)&arr[row * LDB + kofs];
}

// ---------------------------------------------------------------------------
// k_pre (grid 65 x 256): den partials (coalesced) + scalars
// ---------------------------------------------------------------------------
__global__ __launch_bounds__(256) void k_pre(
    const float* __restrict__ beta, const float* __restrict__ exp_n,
    const int* __restrict__ iterp, const int* __restrict__ cmp,
    const int* __restrict__ bcp, float* __restrict__ ws)
{
    const int blk = blockIdx.x, tid = threadIdx.x;
    if (blk < 64) {
        __shared__ float red[256];
        const int k = tid & 63, sub = tid >> 6;
        float p = 0.f;
#pragma unroll
        for (int i = 0; i < 16; i++) {
            const int v = blk * 64 + sub * 16 + i;
            p += beta[v * K_ + k] + exp_n[v * K_ + k];
        }
        red[tid] = p;
        __syncthreads();
        if (tid < 64)
            ws[WS_PART + blk * 64 + tid] =
                red[tid] + red[64 + tid] + red[128 + tid] + red[192 + tid];
    } else {
        if (tid == 0) {
            ws[WS_RHO] = powf((float)(iterp[0] + 5), -0.9f);
            ws[WS_SCALE] = (float)cmp[0] / (float)bcp[0];
        }
    }
}

// ---------------------------------------------------------------------------
// k_main (grid 256 = 4 bt x 64 vt, 256 thr = 4 waves): MFMA path, no atomics.
// ---------------------------------------------------------------------------
__global__ __launch_bounds__(256, 1) void k_main(
    const int* __restrict__ BOW, const int* __restrict__ bidx,
    const float* __restrict__ alpha, const float* __restrict__ pi,
    const float* __restrict__ exp_m, const float* __restrict__ beta,
    const float* __restrict__ exp_n,
    float* __restrict__ ws)
{
    __shared__ __align__(16) float th_s[64 * 68];     // f32 theta (epilogue)
    __shared__ __align__(16) float ph_s[64 * 68];     // f32 phi   (epilogue)
    __shared__ __align__(16) short th_b [64 * LDB];   // bf16 theta[b][k]
    __shared__ __align__(16) short thl_b[64 * LDB];   // bf16 th*log(th)
    __shared__ __align__(16) short ph_b [64 * LDB];   // bf16 phi[v][k]
    __shared__ __align__(16) short phl_b[64 * LDB];   // bf16 ph*log(ph)
    __shared__ __align__(16) short tht_b[64 * LDB];   // bf16 theta^T[k][b]
    __shared__ __align__(16) short pht_b[64 * LDB];   // bf16 phi^T[k][v]
    __shared__ __align__(16) short W_b  [64 * LDB];   // bf16 W[b][v]
    __shared__ __align__(16) short Wt_b [64 * LDB];   // bf16 W^T[v][b]
    __shared__ unsigned char cnt_s[64 * 65];
    __shared__ float dred[256];
    __shared__ float rden_s[64];
    __shared__ float entw[4];
    __shared__ int is64s;
    const int tid = threadIdx.x;
    const int vt = blockIdx.x & 63, bt = blockIdx.x >> 6;
    const int b0 = bt * 64, v0 = vt * 64;

    // ---- den[k] from coalesced partials ----
    if (tid == 0) is64s = detect_is64(bidx);
    {
        const int k = tid & 63, g0 = tid >> 6;
        float s = 0.f;
#pragma unroll
        for (int i = 0; i < 16; i++)
            s += ws[WS_PART + (g0 + 4 * i) * 64 + k];
        dred[tid] = s;
    }
    __syncthreads();
    if (tid < 64)
        rden_s[tid] = __builtin_amdgcn_rcpf(
            dred[tid] + dred[64 + tid] + dred[128 + tid] + dred[192 + tid]);
    __syncthreads();

    {   // ---- staging: row r (0..63), 16-col chunk q (0..3) ----
        const int r = tid >> 2, q = tid & 3;
        const int idx = is64s ? bidx[2 * (b0 + r)] : bidx[b0 + r];
        const int v = v0 + r;
#pragma unroll
        for (int c4 = 0; c4 < 4; c4++) {
            const int k = q * 16 + c4 * 4;
            const float4 a4 = *(const float4*)&alpha[k];
            const float4 p4 = *(const float4*)&pi[idx * K_ + k];
            const float4 m4 = *(const float4*)&exp_m[idx * K_ + k];
            float4 t, tl;
            t.x = a4.x * p4.x + m4.x;  tl.x = t.x * __logf(t.x);
            t.y = a4.y * p4.y + m4.y;  tl.y = t.y * __logf(t.y);
            t.z = a4.z * p4.z + m4.z;  tl.z = t.z * __logf(t.z);
            t.w = a4.w * p4.w + m4.w;  tl.w = t.w * __logf(t.w);
            *(float4*)&th_s[r * 68 + k] = t;
            *(short4*)&th_b [r * LDB + k] = make_short4(bf(t.x), bf(t.y), bf(t.z), bf(t.w));
            *(short4*)&thl_b[r * LDB + k] = make_short4(bf(tl.x), bf(tl.y), bf(tl.z), bf(tl.w));
            tht_b[(k + 0) * LDB + r] = bf(t.x);
            tht_b[(k + 1) * LDB + r] = bf(t.y);
            tht_b[(k + 2) * LDB + r] = bf(t.z);
            tht_b[(k + 3) * LDB + r] = bf(t.w);
            const float4 b4 = *(const float4*)&beta[v * K_ + k];
            const float4 e4 = *(const float4*)&exp_n[v * K_ + k];
            const float4 d4 = *(const float4*)&rden_s[k];
            float4 p, pl;
            p.x = (b4.x + e4.x) * d4.x;  pl.x = p.x * __logf(p.x);
            p.y = (b4.y + e4.y) * d4.y;  pl.y = p.y * __logf(p.y);
            p.z = (b4.z + e4.z) * d4.z;  pl.z = p.z * __logf(p.z);
            p.w = (b4.w + e4.w) * d4.w;  pl.w = p.w * __logf(p.w);
            *(float4*)&ph_s[r * 68 + k] = p;
            *(short4*)&ph_b [r * LDB + k] = make_short4(bf(p.x), bf(p.y), bf(p.z), bf(p.w));
            *(short4*)&phl_b[r * LDB + k] = make_short4(bf(pl.x), bf(pl.y), bf(pl.z), bf(pl.w));
            pht_b[(k + 0) * LDB + r] = bf(p.x);
            pht_b[(k + 1) * LDB + r] = bf(p.y);
            pht_b[(k + 2) * LDB + r] = bf(p.z);
            pht_b[(k + 3) * LDB + r] = bf(p.w);
            const int4 cc = *(const int4*)&BOW[(b0 + r) * V_ + v0 + k];
            cnt_s[r * 65 + k + 0] = (unsigned char)cc.x;
            cnt_s[r * 65 + k + 1] = (unsigned char)cc.y;
            cnt_s[r * 65 + k + 2] = (unsigned char)cc.z;
            cnt_s[r * 65 + k + 3] = (unsigned char)cc.w;
        }
    }
    __syncthreads();

    const int lane = tid & 63, wv = tid >> 6;
    const int l15 = lane & 15, quad = lane >> 4;
    const int qk = quad * 8;                  // k-offset within frag

    // ---- S/E GEMM (MFMA) + W + entropy; wave wv owns b-rows [wv*16, +16) ----
    {
        const int mb = wv * 16;
        const bf16x8 a_t0 = ldfrag(th_b,  mb + l15, 0  + qk);
        const bf16x8 a_t1 = ldfrag(th_b,  mb + l15, 32 + qk);
        const bf16x8 a_l0 = ldfrag(thl_b, mb + l15, 0  + qk);
        const bf16x8 a_l1 = ldfrag(thl_b, mb + l15, 32 + qk);
        float entacc = 0.f;
#pragma unroll
        for (int j = 0; j < 4; j++) {
            const int vrow = j * 16 + l15;
            const bf16x8 b_p0 = ldfrag(ph_b,  vrow, 0  + qk);
            const bf16x8 b_p1 = ldfrag(ph_b,  vrow, 32 + qk);
            const bf16x8 b_l0 = ldfrag(phl_b, vrow, 0  + qk);
            const bf16x8 b_l1 = ldfrag(phl_b, vrow, 32 + qk);
            f32x4 sa = {0.f, 0.f, 0.f, 0.f};
            f32x4 ea = {0.f, 0.f, 0.f, 0.f};
            sa = __builtin_amdgcn_mfma_f32_16x16x32_bf16(a_t0, b_p0, sa, 0, 0, 0);
            sa = __builtin_amdgcn_mfma_f32_16x16x32_bf16(a_t1, b_p1, sa, 0, 0, 0);
            ea = __builtin_amdgcn_mfma_f32_16x16x32_bf16(a_l0, b_p0, ea, 0, 0, 0);
            ea = __builtin_amdgcn_mfma_f32_16x16x32_bf16(a_l1, b_p1, ea, 0, 0, 0);
            ea = __builtin_amdgcn_mfma_f32_16x16x32_bf16(a_t0, b_l0, ea, 0, 0, 0);
            ea = __builtin_amdgcn_mfma_f32_16x16x32_bf16(a_t1, b_l1, ea, 0, 0, 0);
#pragma unroll
            for (int reg = 0; reg < 4; reg++) {
                const int b = mb + quad * 4 + reg;    // D row
                const int v = j * 16 + l15;           // D col
                const float s = sa[reg];
                const float sm = s + MINI;
                const float rr = __builtin_amdgcn_rcpf(sm);
                const int c = (int)cnt_s[b * 65 + v];
                const float w = (float)c * rr;
                W_b [b * LDB + v] = bf(w);
                Wt_b[v * LDB + b] = bf(w);
                if (c) entacc += (ea[reg] - s * __logf(sm)) * rr;
            }
        }
        entacc = wave_sum64(entacc);
        if (lane == 0) entw[wv] = entacc;
    }
    __syncthreads();   // W/Wt published; entw published
    if (tid == 0)
        ws[WS_ENT + blockIdx.x] = entw[0] + entw[1] + entw[2] + entw[3];

    // ---- ten GEMM: D[v,k] = sum_b Wt[v,b]*theta[b,k]; wave owns v-rows ----
    {
        const int mv = wv * 16;
        const bf16x8 wa0 = ldfrag(Wt_b, mv + l15, 0  + qk);
        const bf16x8 wa1 = ldfrag(Wt_b, mv + l15, 32 + qk);
#pragma unroll
        for (int j = 0; j < 4; j++) {
            const bf16x8 bt0 = ldfrag(tht_b, j * 16 + l15, 0  + qk);
            const bf16x8 bt1 = ldfrag(tht_b, j * 16 + l15, 32 + qk);
            f32x4 acc = {0.f, 0.f, 0.f, 0.f};
            acc = __builtin_amdgcn_mfma_f32_16x16x32_bf16(wa0, bt0, acc, 0, 0, 0);
            acc = __builtin_amdgcn_mfma_f32_16x16x32_bf16(wa1, bt1, acc, 0, 0, 0);
#pragma unroll
            for (int reg = 0; reg < 4; reg++) {
                const int v = mv + quad * 4 + reg;
                const int kc = j * 16 + l15;
                ws[WS_TENP + bt * (V_ * K_) + (v0 + v) * K_ + kc] =
                    acc[reg] * ph_s[v * 68 + kc];
            }
        }
    }

    // ---- tem GEMM: D[b,k] = sum_v W[b,v]*phi[v,k]; wave owns b-rows ----
    {
        const int mb = wv * 16;
        const bf16x8 wa0 = ldfrag(W_b, mb + l15, 0  + qk);
        const bf16x8 wa1 = ldfrag(W_b, mb + l15, 32 + qk);
#pragma unroll
        for (int j = 0; j < 4; j++) {
            const bf16x8 bp0 = ldfrag(pht_b, j * 16 + l15, 0  + qk);
            const bf16x8 bp1 = ldfrag(pht_b, j * 16 + l15, 32 + qk);
            f32x4 acc = {0.f, 0.f, 0.f, 0.f};
            acc = __builtin_amdgcn_mfma_f32_16x16x32_bf16(wa0, bp0, acc, 0, 0, 0);
            acc = __builtin_amdgcn_mfma_f32_16x16x32_bf16(wa1, bp1, acc, 0, 0, 0);
#pragma unroll
            for (int reg = 0; reg < 4; reg++) {
                const int b = mb + quad * 4 + reg;
                const int kc = j * 16 + l15;
                ws[WS_TEMP + blockIdx.x * 4096 + b * K_ + kc] =
                    acc[reg] * th_s[b * 68 + kc];
            }
        }
    }
}

// ---------------------------------------------------------------------------
// k_post (grid 321 x 256): reductions + epilogues, no atomics.
// ---------------------------------------------------------------------------
__global__ __launch_bounds__(256) void k_post(
    const int* __restrict__ bidx, const float* __restrict__ exp_n,
    const float* __restrict__ exp_m, const float* __restrict__ ws,
    float* __restrict__ out)
{
    const int blk = blockIdx.x, tid = threadIdx.x;
    if (blk < 256) {
        const float rho = ws[WS_RHO];
        const int t = blk * 256 + tid;              // float4 idx < 65536
        const float4 p0 = *(const float4*)&ws[WS_TENP + 0 * (V_ * K_) + t * 4];
        const float4 p1 = *(const float4*)&ws[WS_TENP + 1 * (V_ * K_) + t * 4];
        const float4 p2 = *(const float4*)&ws[WS_TENP + 2 * (V_ * K_) + t * 4];
        const float4 p3 = *(const float4*)&ws[WS_TENP + 3 * (V_ * K_) + t * 4];
        float4 s;
        s.x = (p0.x + p1.x) + (p2.x + p3.x);
        s.y = (p0.y + p1.y) + (p2.y + p3.y);
        s.z = (p0.z + p1.z) + (p2.z + p3.z);
        s.w = (p0.w + p1.w) + (p2.w + p3.w);
        *(float4*)&out[TEN_OFF + t * 4] = s;
        const float4 e4 = *(const float4*)&exp_n[t * 4];
        const float rs = rho * ws[WS_SCALE];
        out[NEN_OFF + t * 4 + 0] = (1.f - rho) * e4.x + rs * s.x;
        out[NEN_OFF + t * 4 + 1] = (1.f - rho) * e4.y + rs * s.y;
        out[NEN_OFF + t * 4 + 2] = (1.f - rho) * e4.z + rs * s.z;
        out[NEN_OFF + t * 4 + 3] = (1.f - rho) * e4.w + rs * s.w;
    } else if (blk < 320) {
        __shared__ int is64s;
        if (tid == 0) is64s = detect_is64(bidx);
        __syncthreads();
        const float rho = ws[WS_RHO];
        const int b = (blk - 256) * 4 + (tid >> 6);  // < 256
        const int k = tid & 63;
        const int bt = b >> 6, r = b & 63;
        float s = 0.f;
#pragma unroll 8
        for (int vt = 0; vt < 64; vt++)
            s += ws[WS_TEMP + (vt * 4 + bt) * 4096 + r * K_ + k];
        out[TEM_OFF + b * K_ + k] = s;
        const int idx = is64s ? bidx[2 * b] : bidx[b];
        out[NEM_OFF + b * K_ + k] =
            (1.f - rho) * exp_m[idx * K_ + k] + rho * s;
    } else {
        __shared__ float red[256];
        red[tid] = ws[WS_ENT + tid];
        __syncthreads();
        for (int s = 128; s > 0; s >>= 1) {
            if (tid < s) red[tid] += red[tid + s];
            __syncthreads();
        }
        if (tid == 0) out[QZ_OFF] = red[0];
    }
}

extern "C" void kernel_launch(void* const* d_in, const int* in_sizes, int n_in,
                              void* d_out, int out_size, void* d_ws, size_t ws_size,
                              hipStream_t stream)
{
    const int*   BOW   = (const int*)d_in[0];
    const int*   bidx  = (const int*)d_in[1];
    const float* alpha = (const float*)d_in[2];
    const float* pi    = (const float*)d_in[3];
    const float* exp_m = (const float*)d_in[4];
    const float* beta  = (const float*)d_in[5];
    const float* exp_n = (const float*)d_in[6];
    const int*   iterp = (const int*)d_in[7];
    const int*   cmp   = (const int*)d_in[8];
    const int*   bcp   = (const int*)d_in[9];
    float* out = (float*)d_out;
    float* ws  = (float*)d_ws;

    hipLaunchKernelGGL(k_pre, dim3(65), dim3(256), 0, stream,
                       beta, exp_n, iterp, cmp, bcp, ws);
    hipLaunchKernelGGL(k_main, dim3(256), dim3(256), 0, stream,
                       BOW, bidx, alpha, pi, exp_m, beta, exp_n, ws);
    hipLaunchKernelGGL(k_post, dim3(321), dim3(256), 0, stream,
                       bidx, exp_n, exp_m, ws, out);
}

// Round 8
// 92.913 us; speedup vs baseline: 2.9722x; 1.0093x over previous
//
#include <hip/hip_runtime.h>
#include <math.h>

#define B_ 256
#define V_ 4096
#define K_ 64
#define MINI 1e-6f

// ---- output layout (floats, concatenated in reference return order) ----
#define TEN_OFF 0                         // temp_exp_n [V,K]
#define TEM_OFF (V_*K_)                   // temp_exp_m [B,K]   = 262144
#define QZ_OFF  (TEM_OFF + B_*K_)         // exp_q_z scalar     = 278528
#define NEN_OFF (QZ_OFF + 1)              // new_exp_n [V,K]    = 278529 (odd!)
#define NEM_OFF (NEN_OFF + V_*K_)         // new_exp_m [B,K]    = 540673 (odd!)

// ---- workspace layout (floats); ws is 256 MB ----
#define WS_RHO    64
#define WS_SCALE  65
#define WS_PART   128                     // den partials [64 groups][64 k]
#define WS_ENT    4352                    // per-block entropy partials [256]
#define WS_TENP   8192                    // ten partials [4 bt][V,K]
#define WS_TEMP   (WS_TENP + 4*V_*K_)     // tem tiles [256 blk][64 b][64 k]

#define LDB 72                            // bf16 LDS row stride (shorts)

typedef __attribute__((ext_vector_type(8))) short bf16x8;
typedef __attribute__((ext_vector_type(4))) float f32x4;

__device__ __forceinline__ short bf(float x) {
    return (short)(__float_as_uint(x) >> 16);   // truncate f32 -> bf16
}
__device__ __forceinline__ float bf2f(short s) {
    return __uint_as_float(((unsigned int)(unsigned short)s) << 16);
}

__device__ __forceinline__ int detect_is64(const int* bi) {
    int any = 0;
#pragma unroll
    for (int i = 1; i < 64; i += 2) any |= bi[i];
    return any == 0;
}

__device__ __forceinline__ float wave_sum64(float x) {
    x += __shfl_xor(x, 1);
    x += __shfl_xor(x, 2);
    x += __shfl_xor(x, 4);
    x += __shfl_xor(x, 8);
    x += __shfl_xor(x, 16);
    x += __shfl_xor(x, 32);
    return x;
}

__device__ __forceinline__ bf16x8 ldfrag(const short* arr, int row, int kofs) {
    return *(const bf16x8*)&arr[row * LDB + kofs];
}

// ---------------------------------------------------------------------------
// k_pre (grid 65 x 256): den partials (coalesced) + scalars
// ---------------------------------------------------------------------------
__global__ __launch_bounds__(256) void k_pre(
    const float* __restrict__ beta, const float* __restrict__ exp_n,
    const int* __restrict__ iterp, const int* __restrict__ cmp,
    const int* __restrict__ bcp, float* __restrict__ ws)
{
    const int blk = blockIdx.x, tid = threadIdx.x;
    if (blk < 64) {
        __shared__ float red[256];
        const int k = tid & 63, sub = tid >> 6;
        float p = 0.f;
#pragma unroll
        for (int i = 0; i < 16; i++) {
            const int v = blk * 64 + sub * 16 + i;
            p += beta[v * K_ + k] + exp_n[v * K_ + k];
        }
        red[tid] = p;
        __syncthreads();
        if (tid < 64)
            ws[WS_PART + blk * 64 + tid] =
                red[tid] + red[64 + tid] + red[128 + tid] + red[192 + tid];
    } else {
        if (tid == 0) {
            ws[WS_RHO] = powf((float)(iterp[0] + 5), -0.9f);
            ws[WS_SCALE] = (float)cmp[0] / (float)bcp[0];
        }
    }
}

// ---------------------------------------------------------------------------
// k_main (grid 256 = 4 bt x 64 vt, 256 thr = 4 waves): MFMA path, no atomics.
// LDS trimmed to ~79 KB -> 2 blocks/CU (2 waves/SIMD) for latency overlap.
// ---------------------------------------------------------------------------
__global__ __launch_bounds__(256, 2) void k_main(
    const int* __restrict__ BOW, const int* __restrict__ bidx,
    const float* __restrict__ alpha, const float* __restrict__ pi,
    const float* __restrict__ exp_m, const float* __restrict__ beta,
    const float* __restrict__ exp_n,
    float* __restrict__ ws)
{
    __shared__ __align__(16) short th_b [64 * LDB];   // bf16 theta[b][k]
    __shared__ __align__(16) short thl_b[64 * LDB];   // bf16 th*log(th)
    __shared__ __align__(16) short ph_b [64 * LDB];   // bf16 phi[v][k]
    __shared__ __align__(16) short phl_b[64 * LDB];   // bf16 ph*log(ph)
    __shared__ __align__(16) short tht_b[64 * LDB];   // bf16 theta^T[k][b]
    __shared__ __align__(16) short pht_b[64 * LDB];   // bf16 phi^T[k][v]
    __shared__ __align__(16) short W_b  [64 * LDB];   // bf16 W[b][v]
    __shared__ __align__(16) short Wt_b [64 * LDB];   // bf16 W^T[v][b]
    __shared__ unsigned char cnt_s[64 * 65];
    __shared__ float dred[256];
    __shared__ float rden_s[64];
    __shared__ float entw[4];
    __shared__ int is64s;
    const int tid = threadIdx.x;
    const int vt = blockIdx.x & 63, bt = blockIdx.x >> 6;
    const int b0 = bt * 64, v0 = vt * 64;

    // ---- den[k] from coalesced partials ----
    if (tid == 0) is64s = detect_is64(bidx);
    {
        const int k = tid & 63, g0 = tid >> 6;
        float s = 0.f;
#pragma unroll
        for (int i = 0; i < 16; i++)
            s += ws[WS_PART + (g0 + 4 * i) * 64 + k];
        dred[tid] = s;
    }
    __syncthreads();
    if (tid < 64)
        rden_s[tid] = __builtin_amdgcn_rcpf(
            dred[tid] + dred[64 + tid] + dred[128 + tid] + dred[192 + tid]);
    __syncthreads();

    {   // ---- staging: row r (0..63), 16-col chunk q (0..3) ----
        const int r = tid >> 2, q = tid & 3;
        const int idx = is64s ? bidx[2 * (b0 + r)] : bidx[b0 + r];
        const int v = v0 + r;
#pragma unroll
        for (int c4 = 0; c4 < 4; c4++) {
            const int k = q * 16 + c4 * 4;
            const float4 a4 = *(const float4*)&alpha[k];
            const float4 p4 = *(const float4*)&pi[idx * K_ + k];
            const float4 m4 = *(const float4*)&exp_m[idx * K_ + k];
            float4 t, tl;
            t.x = a4.x * p4.x + m4.x;  tl.x = t.x * __logf(t.x);
            t.y = a4.y * p4.y + m4.y;  tl.y = t.y * __logf(t.y);
            t.z = a4.z * p4.z + m4.z;  tl.z = t.z * __logf(t.z);
            t.w = a4.w * p4.w + m4.w;  tl.w = t.w * __logf(t.w);
            *(short4*)&th_b [r * LDB + k] = make_short4(bf(t.x), bf(t.y), bf(t.z), bf(t.w));
            *(short4*)&thl_b[r * LDB + k] = make_short4(bf(tl.x), bf(tl.y), bf(tl.z), bf(tl.w));
            tht_b[(k + 0) * LDB + r] = bf(t.x);
            tht_b[(k + 1) * LDB + r] = bf(t.y);
            tht_b[(k + 2) * LDB + r] = bf(t.z);
            tht_b[(k + 3) * LDB + r] = bf(t.w);
            const float4 b4 = *(const float4*)&beta[v * K_ + k];
            const float4 e4 = *(const float4*)&exp_n[v * K_ + k];
            const float4 d4 = *(const float4*)&rden_s[k];
            float4 p, pl;
            p.x = (b4.x + e4.x) * d4.x;  pl.x = p.x * __logf(p.x);
            p.y = (b4.y + e4.y) * d4.y;  pl.y = p.y * __logf(p.y);
            p.z = (b4.z + e4.z) * d4.z;  pl.z = p.z * __logf(p.z);
            p.w = (b4.w + e4.w) * d4.w;  pl.w = p.w * __logf(p.w);
            *(short4*)&ph_b [r * LDB + k] = make_short4(bf(p.x), bf(p.y), bf(p.z), bf(p.w));
            *(short4*)&phl_b[r * LDB + k] = make_short4(bf(pl.x), bf(pl.y), bf(pl.z), bf(pl.w));
            pht_b[(k + 0) * LDB + r] = bf(p.x);
            pht_b[(k + 1) * LDB + r] = bf(p.y);
            pht_b[(k + 2) * LDB + r] = bf(p.z);
            pht_b[(k + 3) * LDB + r] = bf(p.w);
            const int4 cc = *(const int4*)&BOW[(b0 + r) * V_ + v0 + k];
            cnt_s[r * 65 + k + 0] = (unsigned char)cc.x;
            cnt_s[r * 65 + k + 1] = (unsigned char)cc.y;
            cnt_s[r * 65 + k + 2] = (unsigned char)cc.z;
            cnt_s[r * 65 + k + 3] = (unsigned char)cc.w;
        }
    }
    __syncthreads();

    const int lane = tid & 63, wv = tid >> 6;
    const int l15 = lane & 15, quad = lane >> 4;
    const int qk = quad * 8;                  // k-offset within frag

    // ---- S/E GEMM (MFMA) + W + entropy; wave wv owns b-rows [wv*16, +16) ----
    {
        const int mb = wv * 16;
        const bf16x8 a_t0 = ldfrag(th_b,  mb + l15, 0  + qk);
        const bf16x8 a_t1 = ldfrag(th_b,  mb + l15, 32 + qk);
        const bf16x8 a_l0 = ldfrag(thl_b, mb + l15, 0  + qk);
        const bf16x8 a_l1 = ldfrag(thl_b, mb + l15, 32 + qk);
        float entacc = 0.f;
#pragma unroll
        for (int j = 0; j < 4; j++) {
            const int vrow = j * 16 + l15;
            const bf16x8 b_p0 = ldfrag(ph_b,  vrow, 0  + qk);
            const bf16x8 b_p1 = ldfrag(ph_b,  vrow, 32 + qk);
            const bf16x8 b_l0 = ldfrag(phl_b, vrow, 0  + qk);
            const bf16x8 b_l1 = ldfrag(phl_b, vrow, 32 + qk);
            f32x4 sa = {0.f, 0.f, 0.f, 0.f};
            f32x4 ea = {0.f, 0.f, 0.f, 0.f};
            sa = __builtin_amdgcn_mfma_f32_16x16x32_bf16(a_t0, b_p0, sa, 0, 0, 0);
            sa = __builtin_amdgcn_mfma_f32_16x16x32_bf16(a_t1, b_p1, sa, 0, 0, 0);
            ea = __builtin_amdgcn_mfma_f32_16x16x32_bf16(a_l0, b_p0, ea, 0, 0, 0);
            ea = __builtin_amdgcn_mfma_f32_16x16x32_bf16(a_l1, b_p1, ea, 0, 0, 0);
            ea = __builtin_amdgcn_mfma_f32_16x16x32_bf16(a_t0, b_l0, ea, 0, 0, 0);
            ea = __builtin_amdgcn_mfma_f32_16x16x32_bf16(a_t1, b_l1, ea, 0, 0, 0);
#pragma unroll
            for (int reg = 0; reg < 4; reg++) {
                const int b = mb + quad * 4 + reg;    // D row
                const int v = j * 16 + l15;           // D col
                const float s = sa[reg];
                const float sm = s + MINI;
                const float rr = __builtin_amdgcn_rcpf(sm);
                const int c = (int)cnt_s[b * 65 + v];
                const float w = (float)c * rr;
                W_b [b * LDB + v] = bf(w);
                Wt_b[v * LDB + b] = bf(w);
                if (c) entacc += (ea[reg] - s * __logf(sm)) * rr;
            }
        }
        entacc = wave_sum64(entacc);
        if (lane == 0) entw[wv] = entacc;
    }
    __syncthreads();   // W/Wt published; entw published
    if (tid == 0)
        ws[WS_ENT + blockIdx.x] = entw[0] + entw[1] + entw[2] + entw[3];

    // ---- ten GEMM: D[v,k] = sum_b Wt[v,b]*theta[b,k]; wave owns v-rows ----
    {
        const int mv = wv * 16;
        const bf16x8 wa0 = ldfrag(Wt_b, mv + l15, 0  + qk);
        const bf16x8 wa1 = ldfrag(Wt_b, mv + l15, 32 + qk);
#pragma unroll
        for (int j = 0; j < 4; j++) {
            const bf16x8 bt0 = ldfrag(tht_b, j * 16 + l15, 0  + qk);
            const bf16x8 bt1 = ldfrag(tht_b, j * 16 + l15, 32 + qk);
            f32x4 acc = {0.f, 0.f, 0.f, 0.f};
            acc = __builtin_amdgcn_mfma_f32_16x16x32_bf16(wa0, bt0, acc, 0, 0, 0);
            acc = __builtin_amdgcn_mfma_f32_16x16x32_bf16(wa1, bt1, acc, 0, 0, 0);
#pragma unroll
            for (int reg = 0; reg < 4; reg++) {
                const int v = mv + quad * 4 + reg;
                const int kc = j * 16 + l15;
                ws[WS_TENP + bt * (V_ * K_) + (v0 + v) * K_ + kc] =
                    acc[reg] * bf2f(ph_b[v * LDB + kc]);
            }
        }
    }

    // ---- tem GEMM: D[b,k] = sum_v W[b,v]*phi[v,k]; wave owns b-rows ----
    {
        const int mb = wv * 16;
        const bf16x8 wa0 = ldfrag(W_b, mb + l15, 0  + qk);
        const bf16x8 wa1 = ldfrag(W_b, mb + l15, 32 + qk);
#pragma unroll
        for (int j = 0; j < 4; j++) {
            const bf16x8 bp0 = ldfrag(pht_b, j * 16 + l15, 0  + qk);
            const bf16x8 bp1 = ldfrag(pht_b, j * 16 + l15, 32 + qk);
            f32x4 acc = {0.f, 0.f, 0.f, 0.f};
            acc = __builtin_amdgcn_mfma_f32_16x16x32_bf16(wa0, bp0, acc, 0, 0, 0);
            acc = __builtin_amdgcn_mfma_f32_16x16x32_bf16(wa1, bp1, acc, 0, 0, 0);
#pragma unroll
            for (int reg = 0; reg < 4; reg++) {
                const int b = mb + quad * 4 + reg;
                const int kc = j * 16 + l15;
                ws[WS_TEMP + blockIdx.x * 4096 + b * K_ + kc] =
                    acc[reg] * bf2f(th_b[b * LDB + kc]);
            }
        }
    }
}

// ---------------------------------------------------------------------------
// k_post (grid 321 x 256): reductions + epilogues, no atomics.
// ---------------------------------------------------------------------------
__global__ __launch_bounds__(256) void k_post(
    const int* __restrict__ bidx, const float* __restrict__ exp_n,
    const float* __restrict__ exp_m, const float* __restrict__ ws,
    float* __restrict__ out)
{
    const int blk = blockIdx.x, tid = threadIdx.x;
    if (blk < 256) {
        const float rho = ws[WS_RHO];
        const int t = blk * 256 + tid;              // float4 idx < 65536
        const float4 p0 = *(const float4*)&ws[WS_TENP + 0 * (V_ * K_) + t * 4];
        const float4 p1 = *(const float4*)&ws[WS_TENP + 1 * (V_ * K_) + t * 4];
        const float4 p2 = *(const float4*)&ws[WS_TENP + 2 * (V_ * K_) + t * 4];
        const float4 p3 = *(const float4*)&ws[WS_TENP + 3 * (V_ * K_) + t * 4];
        float4 s;
        s.x = (p0.x + p1.x) + (p2.x + p3.x);
        s.y = (p0.y + p1.y) + (p2.y + p3.y);
        s.z = (p0.z + p1.z) + (p2.z + p3.z);
        s.w = (p0.w + p1.w) + (p2.w + p3.w);
        *(float4*)&out[TEN_OFF + t * 4] = s;
        const float4 e4 = *(const float4*)&exp_n[t * 4];
        const float rs = rho * ws[WS_SCALE];
        out[NEN_OFF + t * 4 + 0] = (1.f - rho) * e4.x + rs * s.x;
        out[NEN_OFF + t * 4 + 1] = (1.f - rho) * e4.y + rs * s.y;
        out[NEN_OFF + t * 4 + 2] = (1.f - rho) * e4.z + rs * s.z;
        out[NEN_OFF + t * 4 + 3] = (1.f - rho) * e4.w + rs * s.w;
    } else if (blk < 320) {
        __shared__ int is64s;
        if (tid == 0) is64s = detect_is64(bidx);
        __syncthreads();
        const float rho = ws[WS_RHO];
        const int b = (blk - 256) * 4 + (tid >> 6);  // < 256
        const int k = tid & 63;
        const int bt = b >> 6, r = b & 63;
        float s = 0.f;
#pragma unroll 8
        for (int vt = 0; vt < 64; vt++)
            s += ws[WS_TEMP + (vt * 4 + bt) * 4096 + r * K_ + k];
        out[TEM_OFF + b * K_ + k] = s;
        const int idx = is64s ? bidx[2 * b] : bidx[b];
        out[NEM_OFF + b * K_ + k] =
            (1.f - rho) * exp_m[idx * K_ + k] + rho * s;
    } else {
        __shared__ float red[256];
        red[tid] = ws[WS_ENT + tid];
        __syncthreads();
        for (int s = 128; s > 0; s >>= 1) {
            if (tid < s) red[tid] += red[tid + s];
            __syncthreads();
        }
        if (tid == 0) out[QZ_OFF] = red[0];
    }
}

extern "C" void kernel_launch(void* const* d_in, const int* in_sizes, int n_in,
                              void* d_out, int out_size, void* d_ws, size_t ws_size,
                              hipStream_t stream)
{
    const int*   BOW   = (const int*)d_in[0];
    const int*   bidx  = (const int*)d_in[1];
    const float* alpha = (const float*)d_in[2];
    const float* pi    = (const float*)d_in[3];
    const float* exp_m = (const float*)d_in[4];
    const float* beta  = (const float*)d_in[5];
    const float* exp_n = (const float*)d_in[6];
    const int*   iterp = (const int*)d_in[7];
    const int*   cmp   = (const int*)d_in[8];
    const int*   bcp   = (const int*)d_in[9];
    float* out = (float*)d_out;
    float* ws  = (float*)d_ws;

    hipLaunchKernelGGL(k_pre, dim3(65), dim3(256), 0, stream,
                       beta, exp_n, iterp, cmp, bcp, ws);
    hipLaunchKernelGGL(k_main, dim3(256), dim3(256), 0, stream,
                       BOW, bidx, alpha, pi, exp_m, beta, exp_n, ws);
    hipLaunchKernelGGL(k_post, dim3(321), dim3(256), 0, stream,
                       bidx, exp_n, exp_m, ws, out);
}